// Round 1
// 304.309 us; speedup vs baseline: 1.0286x; 1.0286x over previous
//
#include <hip/hip_runtime.h>
#include <hip/hip_fp16.h>
#include <math.h>

#define N_NODES 50000
#define N_EDGES 800000
#define F_IN    64
#define H_DIM   128
#define N_GRAPH 512
#define NEG_SLOPE 0.2f
#define SCAN_NB ((N_NODES + 255) / 256)   // 196

typedef __attribute__((ext_vector_type(8))) short short8;   // 8 bf16 (4 VGPRs)
typedef __attribute__((ext_vector_type(4))) float f32x4;
typedef __attribute__((ext_vector_type(2))) float f32x2;

// fp32 -> bf16(hi) + bf16(lo), truncation split (residual ~2^-16 relative)
__device__ __forceinline__ void bsplit(float v, unsigned short& h, unsigned short& l) {
    unsigned u = __float_as_uint(v);
    h = (unsigned short)(u >> 16);
    float hf = __uint_as_float(u & 0xFFFF0000u);
    float r = v - hf;
    l = (unsigned short)(__float_as_uint(r) >> 16);
}
__device__ __forceinline__ float bjoin(unsigned short h, unsigned short l) {
    return __uint_as_float(((unsigned)h) << 16) + __uint_as_float(((unsigned)l) << 16);
}

// ------------------- fused prep: prepX | prepW(frag-major swizzle) | dst-hist(+rank)
#define NB_PX 3125
#define NB_PW 192
#define NB_H  3125
__global__ __launch_bounds__(256) void k_prep(
    const float* __restrict__ x,
    const float* __restrict__ Wl1, const float* __restrict__ Wr1,
    const float* __restrict__ Wl2, const float* __restrict__ Wr2,
    const int* __restrict__ dst,
    unsigned short* __restrict__ Xhi, unsigned short* __restrict__ Xlo,
    unsigned short* __restrict__ WThi, unsigned short* __restrict__ WTlo,
    int* __restrict__ counts, int* __restrict__ rank)
{
    const int bid = blockIdx.x, tid = threadIdx.x;
    if (bid < NB_PX) {
        int i4 = (bid * 256 + tid) * 4;
        if (i4 < N_NODES * F_IN) {
            float4 v = *(const float4*)(x + i4);
            ushort4 h, l;
            bsplit(v.x, h.x, l.x); bsplit(v.y, h.y, l.y);
            bsplit(v.z, h.z, l.z); bsplit(v.w, h.w, l.w);
            *(ushort4*)(Xhi + i4) = h;
            *(ushort4*)(Xlo + i4) = l;
        }
    } else if (bid < NB_PX + NB_PW) {
        int idx = (bid - NB_PX) * 256 + tid;   // 0..49151
        if (idx < 49152) {
            const float* W; int K, li, base, o;
            if (idx < 8192)       { W = Wl1; K = 64;  li = idx;         base = 0;     o = 0; }
            else if (idx < 16384) { W = Wr1; K = 64;  li = idx - 8192;  base = 0;     o = 1; }
            else if (idx < 32768) { W = Wl2; K = 128; li = idx - 16384; base = 16384; o = 0; }
            else                  { W = Wr2; K = 128; li = idx - 32768; base = 16384; o = 1; }
            int c = li / K, k = li - c * K;
            int g = c >> 4, n16 = c & 15;
            int kkblk = k >> 5, quad = (k >> 3) & 3, j = k & 7;
            int off = base + kkblk * 8192 + o * 4096 + g * 512 + (quad * 16 + n16) * 8 + j;
            unsigned short h, l;
            bsplit(W[k * 128 + c], h, l);
            WThi[off] = h; WTlo[off] = l;
        }
    } else {
        int e = (bid - NB_PX - NB_PW) * 256 + tid;
        if (e < N_EDGES) {
            int pos = atomicAdd(&counts[dst[e]], 1);
            rank[e] = pos;
        }
    }
}

// ---------------------------------------------------------------- CSR scans
__global__ __launch_bounds__(256) void k_scan1(const int* __restrict__ counts,
                                               int* __restrict__ excl,
                                               int* __restrict__ partials) {
    __shared__ int s[256];
    int t = threadIdx.x, gid = blockIdx.x * 256 + t;
    int v = (gid < N_NODES) ? counts[gid] : 0;
    s[t] = v;
    __syncthreads();
    for (int off = 1; off < 256; off <<= 1) {
        int x = (t >= off) ? s[t - off] : 0;
        __syncthreads();
        s[t] += x;
        __syncthreads();
    }
    if (gid < N_NODES) excl[gid] = s[t] - v;
    if (t == 255) partials[blockIdx.x] = s[t];
}

__global__ __launch_bounds__(256) void k_scan3(int* __restrict__ offsets,
                                               const int* __restrict__ partials) {
    __shared__ int s[256];
    const int t = threadIdx.x, b = blockIdx.x;
    int v = (t < SCAN_NB) ? partials[t] : 0;
    s[t] = v;
    __syncthreads();
    for (int off = 1; off < 256; off <<= 1) {
        int x = (t >= off) ? s[t - off] : 0;
        __syncthreads();
        s[t] += x;
        __syncthreads();
    }
    int base = (b > 0) ? s[b - 1] : 0;
    int gid = b * 256 + t;
    if (gid < N_NODES) offsets[gid] += base;
    if (gid == 0) offsets[N_NODES] = N_EDGES;
}

// atomic-free CSR scatter (rank precomputed by k_prep's hist phase)
__global__ __launch_bounds__(256) void k_fill(const int* __restrict__ src,
                                              const int* __restrict__ dst,
                                              const int* __restrict__ offsets,
                                              const int* __restrict__ rank,
                                              int* __restrict__ col_src) {
    int e = blockIdx.x * 256 + threadIdx.x;
    if (e < N_EDGES) {
        col_src[offsets[dst[e]] + rank[e]] = src[e];
    }
}

// ---------------------------------------------------------------- MFMA GEMM
// R15-proven: 3-pass bf16-split, 64-row blocks, per-kk staged X tile,
// B-frags direct from fragment-major swizzled W. Output FP16 (halves the
// edge kernel's gather traffic; fp16 rel-err 2^-11 keeps total absmax
// well under threshold).
#define APITCH 40
#define GB_GEMM ((N_NODES + 63) / 64)   // 782
__global__ __launch_bounds__(256, 4) void k_gemm_mfma(
    const unsigned short* __restrict__ Xhi, const unsigned short* __restrict__ Xlo,
    const unsigned short* __restrict__ WThi, const unsigned short* __restrict__ WTlo,
    const float* __restrict__ bl, const float* __restrict__ br,
    unsigned short* __restrict__ OL, unsigned short* __restrict__ OR_, int K)
{
    __shared__ __align__(16) unsigned short Ah[64 * APITCH];
    __shared__ __align__(16) unsigned short Al[64 * APITCH];

    const int tid  = threadIdx.x;
    const int wv   = tid >> 6;        // wave: cols [wv*32, wv*32+32)
    const int lane = tid & 63;
    const int n16  = lane & 15;
    const int quad = lane >> 4;
    const int row0 = blockIdx.x * 64;

    f32x4 acc[4][2][2];               // [rtile][ctile][out]
#pragma unroll
    for (int r = 0; r < 4; ++r)
#pragma unroll
        for (int c = 0; c < 2; ++c)
#pragma unroll
            for (int o = 0; o < 2; ++o) acc[r][c][o] = (f32x4)0.f;

    for (int kk = 0; kk < K; kk += 32) {
        // stage X tile: 64 rows x 32 k, hi+lo. 512 chunks of 16B.
#pragma unroll
        for (int jj = 0; jj < 2; ++jj) {
            int j = tid + jj * 256;
            int part = j >> 8;
            int r = (j & 255) >> 2, sub = j & 3;
            int grow = row0 + r;
            const unsigned short* s = (part ? Xlo : Xhi) + (size_t)grow * K + kk + sub * 8;
            unsigned short* dl = (part ? Al : Ah) + r * APITCH + sub * 8;
            uint4 v = make_uint4(0u, 0u, 0u, 0u);
            if (grow < N_NODES) v = *(const uint4*)s;
            *(uint4*)dl = v;
        }
        __syncthreads();

        // B frags direct from swizzled global (coalesced: lane*8 shorts)
        const unsigned short* wb_h = WThi + (size_t)(kk >> 5) * 8192;
        const unsigned short* wb_l = WTlo + (size_t)(kk >> 5) * 8192;
        short8 bh[2][2], bo[2][2];
#pragma unroll
        for (int c = 0; c < 2; ++c)
#pragma unroll
            for (int o = 0; o < 2; ++o) {
                size_t off = (size_t)o * 4096 + (size_t)(wv * 2 + c) * 512 + (size_t)lane * 8;
                bh[c][o] = *(const short8*)(wb_h + off);
                bo[c][o] = *(const short8*)(wb_l + off);
            }
#pragma unroll
        for (int r = 0; r < 4; ++r) {
            int rl = r * 16 + n16;
            short8 ah = *(const short8*)(Ah + rl * APITCH + quad * 8);
            short8 al = *(const short8*)(Al + rl * APITCH + quad * 8);
#pragma unroll
            for (int c = 0; c < 2; ++c)
#pragma unroll
                for (int o = 0; o < 2; ++o) {
                    f32x4 t = acc[r][c][o];
                    t = __builtin_amdgcn_mfma_f32_16x16x32_bf16(ah, bh[c][o], t, 0, 0, 0);
                    t = __builtin_amdgcn_mfma_f32_16x16x32_bf16(ah, bo[c][o], t, 0, 0, 0);
                    t = __builtin_amdgcn_mfma_f32_16x16x32_bf16(al, bh[c][o], t, 0, 0, 0);
                    acc[r][c][o] = t;
                }
        }
        __syncthreads();
    }

    // epilogue: C/D layout col=lane&15, row=quad*4+reg; store fp16
#pragma unroll
    for (int r = 0; r < 4; ++r)
#pragma unroll
        for (int c = 0; c < 2; ++c)
#pragma unroll
            for (int o = 0; o < 2; ++o) {
                int col = wv * 32 + c * 16 + n16;
                float bb = (o ? br : bl)[col];
                unsigned short* O = o ? OR_ : OL;
#pragma unroll
                for (int g = 0; g < 4; ++g) {
                    int grow = row0 + r * 16 + quad * 4 + g;
                    if (grow < N_NODES) {
                        __half hv = __float2half(acc[r][c][o][g] + bb);
                        O[(size_t)grow * 128 + col] = *(unsigned short*)&hv;
                    }
                }
            }
}

// ---------------------------------------------------------------- edge phase
// 16-lane butterfly sum on the VALU pipe via DPP (no ds_swizzle / lgkmcnt).
// Stages xor1, xor2 via quad_perm; xor4/xor8 via half/row mirror — bit-exact
// equal to the shfl_xor butterfly because values are group-uniform per stage.
__device__ __forceinline__ float red16dpp(float v) {
    v += __int_as_float(__builtin_amdgcn_update_dpp(
             0, __float_as_int(v), 0xB1, 0xF, 0xF, true));   // quad_perm [1,0,3,2]
    v += __int_as_float(__builtin_amdgcn_update_dpp(
             0, __float_as_int(v), 0x4E, 0xF, 0xF, true));   // quad_perm [2,3,0,1]
    v += __int_as_float(__builtin_amdgcn_update_dpp(
             0, __float_as_int(v), 0x141, 0xF, 0xF, true));  // row_half_mirror
    v += __int_as_float(__builtin_amdgcn_update_dpp(
             0, __float_as_int(v), 0x140, 0xF, 0xF, true));  // row_mirror
    return v;
}

// load 8 fp16 (16B) -> four f32x2 (packed-f32 friendly)
__device__ __forceinline__ void load_h8v(const unsigned short* base, size_t off,
                                         f32x2 x[4]) {
    uint4 u = *(const uint4*)(base + off);
    float2 a = __half22float2(*(__half2*)&u.x);
    float2 b = __half22float2(*(__half2*)&u.y);
    float2 c = __half22float2(*(__half2*)&u.z);
    float2 d = __half22float2(*(__half2*)&u.w);
    f32x2 v0 = {a.x, a.y}; x[0] = v0;
    f32x2 v1 = {b.x, b.y}; x[1] = v1;
    f32x2 v2 = {c.x, c.y}; x[2] = v2;
    f32x2 v3 = {d.x, d.y}; x[3] = v3;
}

// att . leaky_relu(x + r) over this lane's 8 dims, packed f32x2.
// leaky(e) = max(e, 0.2e) (identical for all e since slope in (0,1)).
// f32x2 arithmetic selects v_pk_add/mul/fma_f32 on gfx950.
__device__ __forceinline__ float dot8lk(const f32x2 x[4], const f32x2 r[4],
                                        const f32x2 a[4]) {
    f32x2 e0 = x[0] + r[0];
    f32x2 e1 = x[1] + r[1];
    f32x2 l0 = __builtin_elementwise_max(e0, NEG_SLOPE * e0);
    f32x2 l1 = __builtin_elementwise_max(e1, NEG_SLOPE * e1);
    f32x2 s0 = a[0] * l0;
    f32x2 s1 = a[1] * l1;
    f32x2 e2 = x[2] + r[2];
    f32x2 e3 = x[3] + r[3];
    f32x2 l2 = __builtin_elementwise_max(e2, NEG_SLOPE * e2);
    f32x2 l3 = __builtin_elementwise_max(e3, NEG_SLOPE * e3);
    s0 += a[2] * l2;
    s1 += a[3] * l3;
    f32x2 s = s0 + s1;
    return s.x + s.y;
}

// One wave per destination node; 4 quarters of 16 lanes each process a
// different incoming edge. VALU-bound: this version cuts instruction count
// via packed f32, DPP reduce, and deferred-max softmax (rescale only when
// logit > m+8; w bounded by e^8, exact algebra, ample fp32 headroom).
__global__ __launch_bounds__(256) void k_edge(
    const unsigned short* __restrict__ xl, const unsigned short* __restrict__ xr,
    const float* __restrict__ att, const float* __restrict__ bias,
    const int* __restrict__ offsets, const int* __restrict__ col_src,
    unsigned short* __restrict__ outHi, unsigned short* __restrict__ outLo)
{
    int d = blockIdx.x * 4 + (threadIdx.x >> 6);
    if (d >= N_NODES) return;
    const int lane = threadIdx.x & 63;
    const int q = lane >> 4;
    const int t = lane & 15;
    const size_t dim0 = (size_t)t * 8;

    f32x2 rr[4], aa[4], xs[4];
    load_h8v(xr, (size_t)d * 128 + dim0, rr);
    {
        const float4 a0 = *(const float4*)(att + dim0);
        const float4 a1 = *(const float4*)(att + dim0 + 4);
        f32x2 w0 = {a0.x, a0.y}; aa[0] = w0;
        f32x2 w1 = {a0.z, a0.w}; aa[1] = w1;
        f32x2 w2 = {a1.x, a1.y}; aa[2] = w2;
        f32x2 w3 = {a1.z, a1.w}; aa[3] = w3;
    }
    load_h8v(xl, (size_t)d * 128 + dim0, xs);
    float sl = red16dpp(dot8lk(xs, rr, aa));   // identical in all 64 lanes

    // deferred-max online softmax: m is a reference >= logit-8 for all
    // accumulated terms; every quarter starts at the self-loop logit.
    float m = sl, thr = sl + 8.f;
    float lsum = (q == 0) ? 1.f : 0.f;
    f32x2 zero = {0.f, 0.f};
    f32x2 acc[4];
#pragma unroll
    for (int j = 0; j < 4; ++j) acc[j] = (q == 0) ? xs[j] : zero;

    const int ibeg = offsets[d], iend = offsets[d + 1];
    for (int base = ibeg; base < iend; base += 4) {
        int i = base + q;
        bool valid = (i < iend);
        int s = valid ? col_src[i] : d;      // pad with self row: logit=sl<=m, w zeroed
        f32x2 x[4];
        load_h8v(xl, (size_t)s * 128 + dim0, x);
        float logit = red16dpp(dot8lk(x, rr, aa));   // quarter-uniform
        if (__builtin_expect(logit > thr, 0)) {      // rare rescale path
            float sc = __expf(m - logit);
            lsum *= sc;
#pragma unroll
            for (int j = 0; j < 4; ++j) acc[j] = acc[j] * sc;
            m = logit; thr = logit + 8.f;
        }
        float w = valid ? __expf(logit - m) : 0.f;   // <= e^8
        lsum += w;
        f32x2 w2 = {w, w};
#pragma unroll
        for (int j = 0; j < 4; ++j) acc[j] += w2 * x[j];   // pk_fma
    }

    // merge the 4 quarters (each holds partials relative to its own m)
    float M = m;
    M = fmaxf(M, __shfl_xor(M, 16));
    M = fmaxf(M, __shfl_xor(M, 32));
    float sc = __expf(m - M);
    lsum *= sc;
    f32x2 sc2 = {sc, sc};
#pragma unroll
    for (int j = 0; j < 4; ++j) acc[j] = acc[j] * sc2;
#pragma unroll
    for (int off = 16; off <= 32; off <<= 1) {
        lsum += __shfl_xor(lsum, off);
#pragma unroll
        for (int j = 0; j < 4; ++j) {
            acc[j].x += __shfl_xor(acc[j].x, off);
            acc[j].y += __shfl_xor(acc[j].y, off);
        }
    }

    if (q == 0) {
        float inv = 1.f / lsum;
        const float4 b0 = *(const float4*)(bias + dim0);
        const float4 b1 = *(const float4*)(bias + dim0 + 4);
        float bv[8] = {b0.x, b0.y, b0.z, b0.w, b1.x, b1.y, b1.z, b1.w};
        float v[8];
#pragma unroll
        for (int j = 0; j < 4; ++j) {
            v[2 * j]     = fmaxf(fmaf(acc[j].x, inv, bv[2 * j]), 0.f);
            v[2 * j + 1] = fmaxf(fmaf(acc[j].y, inv, bv[2 * j + 1]), 0.f);
        }
        union { unsigned short s[8]; uint4 u; } Hh, Ll;
#pragma unroll
        for (int i2 = 0; i2 < 8; ++i2) bsplit(v[i2], Hh.s[i2], Ll.s[i2]);
        *(uint4*)(outHi + (size_t)d * 128 + dim0) = Hh.u;
        *(uint4*)(outLo + (size_t)d * 128 + dim0) = Ll.u;
    }
}

// ---------------------------------------------------------------- pooling
__global__ __launch_bounds__(256) void k_pool(
    const unsigned short* __restrict__ hHi, const unsigned short* __restrict__ hLo,
    const int* __restrict__ batch,
    float* __restrict__ psum, float* __restrict__ pcnt)
{
    const int tid = threadIdx.x;
    const int tx = tid & 31;
    const int ty = tid >> 5;
    const int n0 = blockIdx.x * 64;
    const int d0 = tx * 4;

    float4 acc = make_float4(0.f, 0.f, 0.f, 0.f);
    int cur = -1, crun = 0;
#pragma unroll
    for (int it = 0; it < 8; ++it) {
        int n = n0 + it * 8 + ty;
        if (n < N_NODES) {
            int g = batch[n];
            if (g != cur) {
                if (cur >= 0) {
                    atomicAdd(&psum[cur * 128 + d0 + 0], acc.x);
                    atomicAdd(&psum[cur * 128 + d0 + 1], acc.y);
                    atomicAdd(&psum[cur * 128 + d0 + 2], acc.z);
                    atomicAdd(&psum[cur * 128 + d0 + 3], acc.w);
                    if (tx == 0) atomicAdd(&pcnt[cur], (float)crun);
                }
                cur = g; acc = make_float4(0.f, 0.f, 0.f, 0.f); crun = 0;
            }
            ushort4 h = *(const ushort4*)(hHi + (size_t)n * 128 + d0);
            ushort4 l = *(const ushort4*)(hLo + (size_t)n * 128 + d0);
            acc.x += bjoin(h.x, l.x);
            acc.y += bjoin(h.y, l.y);
            acc.z += bjoin(h.z, l.z);
            acc.w += bjoin(h.w, l.w);
            crun++;
        }
    }
    if (cur >= 0) {
        atomicAdd(&psum[cur * 128 + d0 + 0], acc.x);
        atomicAdd(&psum[cur * 128 + d0 + 1], acc.y);
        atomicAdd(&psum[cur * 128 + d0 + 2], acc.z);
        atomicAdd(&psum[cur * 128 + d0 + 3], acc.w);
        if (tx == 0) atomicAdd(&pcnt[cur], (float)crun);
    }
}

// ---------------------------------------------------------------- head
__global__ __launch_bounds__(256) void k_head(
    const float* __restrict__ psum, const float* __restrict__ pcnt,
    const float* __restrict__ Wlin, const float* __restrict__ blin,
    float* __restrict__ out)
{
    int g = blockIdx.x * 4 + (threadIdx.x >> 6);
    if (g >= N_GRAPH) return;
    int lane = threadIdx.x & 63;
    float c = fmaxf(pcnt[g], 1.f);
    float2 s = *(const float2*)(psum + (size_t)g * 128 + lane * 2);
    float p = (s.x * Wlin[lane * 2] + s.y * Wlin[lane * 2 + 1]) / c;
#pragma unroll
    for (int off = 32; off > 0; off >>= 1) p += __shfl_xor(p, off);
    if (lane == 0) out[g] = p + blin[0];
}

// ---------------------------------------------------------------- launch
extern "C" void kernel_launch(void* const* d_in, const int* in_sizes, int n_in,
                              void* d_out, int out_size, void* d_ws, size_t ws_size,
                              hipStream_t stream) {
    const float* x     = (const float*)d_in[0];
    const int*   ei    = (const int*)d_in[1];
    const int*   batch = (const int*)d_in[3];
    const float* Wl1 = (const float*)d_in[4],  *bl1 = (const float*)d_in[5];
    const float* Wr1 = (const float*)d_in[6],  *br1 = (const float*)d_in[7];
    const float* att1= (const float*)d_in[8],  *b1  = (const float*)d_in[9];
    const float* Wl2 = (const float*)d_in[10], *bl2 = (const float*)d_in[11];
    const float* Wr2 = (const float*)d_in[12], *br2 = (const float*)d_in[13];
    const float* att2= (const float*)d_in[14], *b2  = (const float*)d_in[15];
    const float* Wlin= (const float*)d_in[16], *blin= (const float*)d_in[17];
    float* out = (float*)d_out;

    const int* src = ei;
    const int* dst = ei + N_EDGES;

    char* p = (char*)d_ws;
    auto carve = [&](size_t bytes) {
        void* r = (void*)p;
        p += (bytes + 255) & ~(size_t)255;
        return r;
    };
    unsigned short* bufA   = (unsigned short*)carve((size_t)N_NODES * 128 * 2); // xl fp16
    unsigned short* bufB   = (unsigned short*)carve((size_t)N_NODES * 128 * 2); // xr fp16
    unsigned short* Hhi    = (unsigned short*)carve((size_t)N_NODES * 128 * 2);
    unsigned short* Hlo    = (unsigned short*)carve((size_t)N_NODES * 128 * 2);
    unsigned short* Xhi1   = (unsigned short*)carve((size_t)N_NODES * 64 * 2);
    unsigned short* Xlo1   = (unsigned short*)carve((size_t)N_NODES * 64 * 2);
    unsigned short* WThi   = (unsigned short*)carve(49152 * 2);
    unsigned short* WTlo   = (unsigned short*)carve(49152 * 2);
    int*            offsets= (int*)carve((size_t)(N_NODES + 1) * 4);
    int*            rank   = (int*)carve((size_t)N_EDGES * 4);
    int*            partials=(int*)carve(256 * 4);
    int*            col_src= (int*)carve((size_t)N_EDGES * 4);
    // zero region: counts | psum | pcnt
    char* zb = (char*)carve(200192 + 262144 + 2048);
    int*   counts = (int*)zb;
    float* psum   = (float*)(zb + 200192);
    float* pcnt   = (float*)(zb + 200192 + 262144);
    const size_t zbytes = 200192 + 262144 + 2048;

    hipMemsetAsync(zb, 0, zbytes, stream);

    k_prep<<<NB_PX + NB_PW + NB_H, 256, 0, stream>>>(
        x, Wl1, Wr1, Wl2, Wr2, dst,
        Xhi1, Xlo1, WThi, WTlo, counts, rank);
    k_scan1<<<SCAN_NB, 256, 0, stream>>>(counts, offsets, partials);
    k_scan3<<<SCAN_NB, 256, 0, stream>>>(offsets, partials);
    k_fill <<<(N_EDGES + 255) / 256, 256, 0, stream>>>(src, dst, offsets, rank, col_src);

    // layer 1 (K=64)
    k_gemm_mfma<<<GB_GEMM, 256, 0, stream>>>(Xhi1, Xlo1, WThi, WTlo,
                                             bl1, br1, bufA, bufB, F_IN);
    k_edge<<<(N_NODES + 3) / 4, 256, 0, stream>>>(
        bufA, bufB, att1, b1, offsets, col_src, Hhi, Hlo);
    // layer 2 (K=128)
    k_gemm_mfma<<<GB_GEMM, 256, 0, stream>>>(Hhi, Hlo, WThi + 16384, WTlo + 16384,
                                             bl2, br2, bufA, bufB, H_DIM);
    k_edge<<<(N_NODES + 3) / 4, 256, 0, stream>>>(
        bufA, bufB, att2, b2, offsets, col_src, Hhi, Hlo);
    // pool + head
    k_pool<<<(N_NODES + 63) / 64, 256, 0, stream>>>(Hhi, Hlo, batch, psum, pcnt);
    k_head<<<(N_GRAPH + 3) / 4, 256, 0, stream>>>(psum, pcnt, Wlin, blin, out);
}

// Round 2
// 299.489 us; speedup vs baseline: 1.0451x; 1.0161x over previous
//
#include <hip/hip_runtime.h>
#include <hip/hip_fp16.h>
#include <math.h>

#define N_NODES 50000
#define N_EDGES 800000
#define F_IN    64
#define H_DIM   128
#define N_GRAPH 512
#define NEG_SLOPE 0.2f
#define SCAN_NB ((N_NODES + 255) / 256)   // 196

typedef __attribute__((ext_vector_type(8))) short short8;   // 8 bf16 (4 VGPRs)
typedef __attribute__((ext_vector_type(4))) float f32x4;
typedef __attribute__((ext_vector_type(2))) float f32x2;

// fp32 -> bf16(hi) + bf16(lo), truncation split (residual ~2^-16 relative)
__device__ __forceinline__ void bsplit(float v, unsigned short& h, unsigned short& l) {
    unsigned u = __float_as_uint(v);
    h = (unsigned short)(u >> 16);
    float hf = __uint_as_float(u & 0xFFFF0000u);
    float r = v - hf;
    l = (unsigned short)(__float_as_uint(r) >> 16);
}
__device__ __forceinline__ float bjoin(unsigned short h, unsigned short l) {
    return __uint_as_float(((unsigned)h) << 16) + __uint_as_float(((unsigned)l) << 16);
}

// ------------------- prep: prepX | prepW(frag-major swizzle)  (hist moved out)
#define NB_PX 3125
#define NB_PW 192
__global__ __launch_bounds__(256) void k_prep(
    const float* __restrict__ x,
    const float* __restrict__ Wl1, const float* __restrict__ Wr1,
    const float* __restrict__ Wl2, const float* __restrict__ Wr2,
    unsigned short* __restrict__ Xhi, unsigned short* __restrict__ Xlo,
    unsigned short* __restrict__ WThi, unsigned short* __restrict__ WTlo)
{
    const int bid = blockIdx.x, tid = threadIdx.x;
    if (bid < NB_PX) {
        int i4 = (bid * 256 + tid) * 4;
        if (i4 < N_NODES * F_IN) {
            float4 v = *(const float4*)(x + i4);
            ushort4 h, l;
            bsplit(v.x, h.x, l.x); bsplit(v.y, h.y, l.y);
            bsplit(v.z, h.z, l.z); bsplit(v.w, h.w, l.w);
            *(ushort4*)(Xhi + i4) = h;
            *(ushort4*)(Xlo + i4) = l;
        }
    } else {
        int idx = (bid - NB_PX) * 256 + tid;   // 0..49151
        if (idx < 49152) {
            const float* W; int K, li, base, o;
            if (idx < 8192)       { W = Wl1; K = 64;  li = idx;         base = 0;     o = 0; }
            else if (idx < 16384) { W = Wr1; K = 64;  li = idx - 8192;  base = 0;     o = 1; }
            else if (idx < 32768) { W = Wl2; K = 128; li = idx - 16384; base = 16384; o = 0; }
            else                  { W = Wr2; K = 128; li = idx - 32768; base = 16384; o = 1; }
            int c = li / K, k = li - c * K;
            int g = c >> 4, n16 = c & 15;
            int kkblk = k >> 5, quad = (k >> 3) & 3, j = k & 7;
            int off = base + kkblk * 8192 + o * 4096 + g * 512 + (quad * 16 + n16) * 8 + j;
            unsigned short h, l;
            bsplit(W[k * 128 + c], h, l);
            WThi[off] = h; WTlo[off] = l;
        }
    }
}

// ---------------------------------------------------------------- CSR scans
// counts is PADDED: one counter per 64B line (stride 16 ints) to kill
// same-line atomic serialization (256 ops/line -> 16 ops/line).
__global__ __launch_bounds__(256) void k_scan1(const int* __restrict__ counts,
                                               int* __restrict__ excl,
                                               int* __restrict__ partials) {
    __shared__ int s[256];
    int t = threadIdx.x, gid = blockIdx.x * 256 + t;
    int v = (gid < N_NODES) ? counts[gid << 4] : 0;
    s[t] = v;
    __syncthreads();
    for (int off = 1; off < 256; off <<= 1) {
        int x = (t >= off) ? s[t - off] : 0;
        __syncthreads();
        s[t] += x;
        __syncthreads();
    }
    if (gid < N_NODES) excl[gid] = s[t] - v;
    if (t == 255) partials[blockIdx.x] = s[t];
}

__global__ __launch_bounds__(256) void k_scan3(int* __restrict__ offsets,
                                               const int* __restrict__ partials) {
    __shared__ int s[256];
    const int t = threadIdx.x, b = blockIdx.x;
    int v = (t < SCAN_NB) ? partials[t] : 0;
    s[t] = v;
    __syncthreads();
    for (int off = 1; off < 256; off <<= 1) {
        int x = (t >= off) ? s[t - off] : 0;
        __syncthreads();
        s[t] += x;
        __syncthreads();
    }
    int base = (b > 0) ? s[b - 1] : 0;
    int gid = b * 256 + t;
    if (gid < N_NODES) offsets[gid] += base;
    if (gid == 0) offsets[N_NODES] = N_EDGES;
}

// atomic-free CSR scatter (rank precomputed by the fused hist phase)
__global__ __launch_bounds__(256) void k_fill(const int* __restrict__ src,
                                              const int* __restrict__ dst,
                                              const int* __restrict__ offsets,
                                              const int* __restrict__ rank,
                                              int* __restrict__ col_src) {
    int e = blockIdx.x * 256 + threadIdx.x;
    if (e < N_EDGES) {
        col_src[offsets[dst[e]] + rank[e]] = src[e];
    }
}

// ---------------------------------------------------------------- MFMA GEMM
// R15-proven: 3-pass bf16-split, 64-row blocks, per-kk staged X tile,
// B-frags direct from fragment-major swizzled W. Output FP16.
#define APITCH 40
#define GB_GEMM ((N_NODES + 63) / 64)   // 782
#define GB_HIST ((N_EDGES + 255) / 256) // 3125

__device__ __forceinline__ void gemm_body(
    unsigned short* __restrict__ Ah, unsigned short* __restrict__ Al,
    const unsigned short* __restrict__ Xhi, const unsigned short* __restrict__ Xlo,
    const unsigned short* __restrict__ WThi, const unsigned short* __restrict__ WTlo,
    const float* __restrict__ bl, const float* __restrict__ br,
    unsigned short* __restrict__ OL, unsigned short* __restrict__ OR_,
    int K, int blk)
{
    const int tid  = threadIdx.x;
    const int wv   = tid >> 6;        // wave: cols [wv*32, wv*32+32)
    const int lane = tid & 63;
    const int n16  = lane & 15;
    const int quad = lane >> 4;
    const int row0 = blk * 64;

    f32x4 acc[4][2][2];               // [rtile][ctile][out]
#pragma unroll
    for (int r = 0; r < 4; ++r)
#pragma unroll
        for (int c = 0; c < 2; ++c)
#pragma unroll
            for (int o = 0; o < 2; ++o) acc[r][c][o] = (f32x4)0.f;

    for (int kk = 0; kk < K; kk += 32) {
        // stage X tile: 64 rows x 32 k, hi+lo. 512 chunks of 16B.
#pragma unroll
        for (int jj = 0; jj < 2; ++jj) {
            int j = tid + jj * 256;
            int part = j >> 8;
            int r = (j & 255) >> 2, sub = j & 3;
            int grow = row0 + r;
            const unsigned short* s = (part ? Xlo : Xhi) + (size_t)grow * K + kk + sub * 8;
            unsigned short* dl = (part ? Al : Ah) + r * APITCH + sub * 8;
            uint4 v = make_uint4(0u, 0u, 0u, 0u);
            if (grow < N_NODES) v = *(const uint4*)s;
            *(uint4*)dl = v;
        }
        __syncthreads();

        // B frags direct from swizzled global (coalesced: lane*8 shorts)
        const unsigned short* wb_h = WThi + (size_t)(kk >> 5) * 8192;
        const unsigned short* wb_l = WTlo + (size_t)(kk >> 5) * 8192;
        short8 bh[2][2], bo[2][2];
#pragma unroll
        for (int c = 0; c < 2; ++c)
#pragma unroll
            for (int o = 0; o < 2; ++o) {
                size_t off = (size_t)o * 4096 + (size_t)(wv * 2 + c) * 512 + (size_t)lane * 8;
                bh[c][o] = *(const short8*)(wb_h + off);
                bo[c][o] = *(const short8*)(wb_l + off);
            }
#pragma unroll
        for (int r = 0; r < 4; ++r) {
            int rl = r * 16 + n16;
            short8 ah = *(const short8*)(Ah + rl * APITCH + quad * 8);
            short8 al = *(const short8*)(Al + rl * APITCH + quad * 8);
#pragma unroll
            for (int c = 0; c < 2; ++c)
#pragma unroll
                for (int o = 0; o < 2; ++o) {
                    f32x4 t = acc[r][c][o];
                    t = __builtin_amdgcn_mfma_f32_16x16x32_bf16(ah, bh[c][o], t, 0, 0, 0);
                    t = __builtin_amdgcn_mfma_f32_16x16x32_bf16(ah, bo[c][o], t, 0, 0, 0);
                    t = __builtin_amdgcn_mfma_f32_16x16x32_bf16(al, bh[c][o], t, 0, 0, 0);
                    acc[r][c][o] = t;
                }
        }
        __syncthreads();
    }

    // epilogue: C/D layout col=lane&15, row=quad*4+reg; store fp16
#pragma unroll
    for (int r = 0; r < 4; ++r)
#pragma unroll
        for (int c = 0; c < 2; ++c)
#pragma unroll
            for (int o = 0; o < 2; ++o) {
                int col = wv * 32 + c * 16 + n16;
                float bb = (o ? br : bl)[col];
                unsigned short* O = o ? OR_ : OL;
#pragma unroll
                for (int g = 0; g < 4; ++g) {
                    int grow = row0 + r * 16 + quad * 4 + g;
                    if (grow < N_NODES) {
                        __half hv = __float2half(acc[r][c][o][g] + bb);
                        O[(size_t)grow * 128 + col] = *(unsigned short*)&hv;
                    }
                }
            }
}

__global__ __launch_bounds__(256, 4) void k_gemm_mfma(
    const unsigned short* __restrict__ Xhi, const unsigned short* __restrict__ Xlo,
    const unsigned short* __restrict__ WThi, const unsigned short* __restrict__ WTlo,
    const float* __restrict__ bl, const float* __restrict__ br,
    unsigned short* __restrict__ OL, unsigned short* __restrict__ OR_, int K)
{
    __shared__ __align__(16) unsigned short Ah[64 * APITCH];
    __shared__ __align__(16) unsigned short Al[64 * APITCH];
    gemm_body(Ah, Al, Xhi, Xlo, WThi, WTlo, bl, br, OL, OR_, K, blockIdx.x);
}

// layer-1 GEMM fused with the dst-histogram: gemm blocks first (MFMA from
// t=0), 3125 latency-bound atomic blocks fill remaining CU slots and hide
// under the GEMM. counts padded to 1 counter / 64B line.
__global__ __launch_bounds__(256, 4) void k_gemm1_hist(
    const unsigned short* __restrict__ Xhi, const unsigned short* __restrict__ Xlo,
    const unsigned short* __restrict__ WThi, const unsigned short* __restrict__ WTlo,
    const float* __restrict__ bl, const float* __restrict__ br,
    unsigned short* __restrict__ OL, unsigned short* __restrict__ OR_, int K,
    const int* __restrict__ dst, int* __restrict__ counts, int* __restrict__ rank)
{
    __shared__ __align__(16) unsigned short Ah[64 * APITCH];
    __shared__ __align__(16) unsigned short Al[64 * APITCH];
    if (blockIdx.x < GB_GEMM) {
        gemm_body(Ah, Al, Xhi, Xlo, WThi, WTlo, bl, br, OL, OR_, K, blockIdx.x);
    } else {
        int e = (blockIdx.x - GB_GEMM) * 256 + threadIdx.x;
        if (e < N_EDGES) {
            rank[e] = atomicAdd(&counts[dst[e] << 4], 1);
        }
    }
}

// ---------------------------------------------------------------- edge phase
// 16-lane butterfly sum on the VALU pipe via DPP (no ds_swizzle / lgkmcnt).
__device__ __forceinline__ float red16dpp(float v) {
    v += __int_as_float(__builtin_amdgcn_update_dpp(
             0, __float_as_int(v), 0xB1, 0xF, 0xF, true));   // quad_perm [1,0,3,2]
    v += __int_as_float(__builtin_amdgcn_update_dpp(
             0, __float_as_int(v), 0x4E, 0xF, 0xF, true));   // quad_perm [2,3,0,1]
    v += __int_as_float(__builtin_amdgcn_update_dpp(
             0, __float_as_int(v), 0x141, 0xF, 0xF, true));  // row_half_mirror
    v += __int_as_float(__builtin_amdgcn_update_dpp(
             0, __float_as_int(v), 0x140, 0xF, 0xF, true));  // row_mirror
    return v;
}

// load 8 fp16 (16B) -> four f32x2 (packed-f32 friendly)
__device__ __forceinline__ void load_h8v(const unsigned short* base, size_t off,
                                         f32x2 x[4]) {
    uint4 u = *(const uint4*)(base + off);
    float2 a = __half22float2(*(__half2*)&u.x);
    float2 b = __half22float2(*(__half2*)&u.y);
    float2 c = __half22float2(*(__half2*)&u.z);
    float2 d = __half22float2(*(__half2*)&u.w);
    f32x2 v0 = {a.x, a.y}; x[0] = v0;
    f32x2 v1 = {b.x, b.y}; x[1] = v1;
    f32x2 v2 = {c.x, c.y}; x[2] = v2;
    f32x2 v3 = {d.x, d.y}; x[3] = v3;
}

// att . leaky_relu(x + r) over this lane's 8 dims, packed f32x2.
__device__ __forceinline__ float dot8lk(const f32x2 x[4], const f32x2 r[4],
                                        const f32x2 a[4]) {
    f32x2 e0 = x[0] + r[0];
    f32x2 e1 = x[1] + r[1];
    f32x2 l0 = __builtin_elementwise_max(e0, NEG_SLOPE * e0);
    f32x2 l1 = __builtin_elementwise_max(e1, NEG_SLOPE * e1);
    f32x2 s0 = a[0] * l0;
    f32x2 s1 = a[1] * l1;
    f32x2 e2 = x[2] + r[2];
    f32x2 e3 = x[3] + r[3];
    f32x2 l2 = __builtin_elementwise_max(e2, NEG_SLOPE * e2);
    f32x2 l3 = __builtin_elementwise_max(e3, NEG_SLOPE * e3);
    s0 += a[2] * l2;
    s1 += a[3] * l3;
    f32x2 s = s0 + s1;
    return s.x + s.y;
}

// One wave per destination node; 4 quarters of 16 lanes each process a
// different incoming edge. Packed f32, DPP reduce, deferred-max softmax.
__global__ __launch_bounds__(256) void k_edge(
    const unsigned short* __restrict__ xl, const unsigned short* __restrict__ xr,
    const float* __restrict__ att, const float* __restrict__ bias,
    const int* __restrict__ offsets, const int* __restrict__ col_src,
    unsigned short* __restrict__ outHi, unsigned short* __restrict__ outLo)
{
    int d = blockIdx.x * 4 + (threadIdx.x >> 6);
    if (d >= N_NODES) return;
    const int lane = threadIdx.x & 63;
    const int q = lane >> 4;
    const int t = lane & 15;
    const size_t dim0 = (size_t)t * 8;

    f32x2 rr[4], aa[4], xs[4];
    load_h8v(xr, (size_t)d * 128 + dim0, rr);
    {
        const float4 a0 = *(const float4*)(att + dim0);
        const float4 a1 = *(const float4*)(att + dim0 + 4);
        f32x2 w0 = {a0.x, a0.y}; aa[0] = w0;
        f32x2 w1 = {a0.z, a0.w}; aa[1] = w1;
        f32x2 w2 = {a1.x, a1.y}; aa[2] = w2;
        f32x2 w3 = {a1.z, a1.w}; aa[3] = w3;
    }
    load_h8v(xl, (size_t)d * 128 + dim0, xs);
    float sl = red16dpp(dot8lk(xs, rr, aa));   // identical in all 64 lanes

    // deferred-max online softmax: m is a reference >= logit-8 for all
    // accumulated terms; every quarter starts at the self-loop logit.
    float m = sl, thr = sl + 8.f;
    float lsum = (q == 0) ? 1.f : 0.f;
    f32x2 zero = {0.f, 0.f};
    f32x2 acc[4];
#pragma unroll
    for (int j = 0; j < 4; ++j) acc[j] = (q == 0) ? xs[j] : zero;

    const int ibeg = offsets[d], iend = offsets[d + 1];
    for (int base = ibeg; base < iend; base += 4) {
        int i = base + q;
        bool valid = (i < iend);
        int s = valid ? col_src[i] : d;      // pad with self row: logit=sl<=m, w zeroed
        f32x2 x[4];
        load_h8v(xl, (size_t)s * 128 + dim0, x);
        float logit = red16dpp(dot8lk(x, rr, aa));   // quarter-uniform
        if (__builtin_expect(logit > thr, 0)) {      // rare rescale path
            float sc = __expf(m - logit);
            lsum *= sc;
#pragma unroll
            for (int j = 0; j < 4; ++j) acc[j] = acc[j] * sc;
            m = logit; thr = logit + 8.f;
        }
        float w = valid ? __expf(logit - m) : 0.f;   // <= e^8
        lsum += w;
        f32x2 w2 = {w, w};
#pragma unroll
        for (int j = 0; j < 4; ++j) acc[j] += w2 * x[j];   // pk_fma
    }

    // merge the 4 quarters (each holds partials relative to its own m)
    float M = m;
    M = fmaxf(M, __shfl_xor(M, 16));
    M = fmaxf(M, __shfl_xor(M, 32));
    float sc = __expf(m - M);
    lsum *= sc;
    f32x2 sc2 = {sc, sc};
#pragma unroll
    for (int j = 0; j < 4; ++j) acc[j] = acc[j] * sc2;
#pragma unroll
    for (int off = 16; off <= 32; off <<= 1) {
        lsum += __shfl_xor(lsum, off);
#pragma unroll
        for (int j = 0; j < 4; ++j) {
            acc[j].x += __shfl_xor(acc[j].x, off);
            acc[j].y += __shfl_xor(acc[j].y, off);
        }
    }

    if (q == 0) {
        float inv = 1.f / lsum;
        const float4 b0 = *(const float4*)(bias + dim0);
        const float4 b1 = *(const float4*)(bias + dim0 + 4);
        float bv[8] = {b0.x, b0.y, b0.z, b0.w, b1.x, b1.y, b1.z, b1.w};
        float v[8];
#pragma unroll
        for (int j = 0; j < 4; ++j) {
            v[2 * j]     = fmaxf(fmaf(acc[j].x, inv, bv[2 * j]), 0.f);
            v[2 * j + 1] = fmaxf(fmaf(acc[j].y, inv, bv[2 * j + 1]), 0.f);
        }
        union { unsigned short s[8]; uint4 u; } Hh, Ll;
#pragma unroll
        for (int i2 = 0; i2 < 8; ++i2) bsplit(v[i2], Hh.s[i2], Ll.s[i2]);
        *(uint4*)(outHi + (size_t)d * 128 + dim0) = Hh.u;
        *(uint4*)(outLo + (size_t)d * 128 + dim0) = Ll.u;
    }
}

// ---------------------------------------------------------------- pooling
__global__ __launch_bounds__(256) void k_pool(
    const unsigned short* __restrict__ hHi, const unsigned short* __restrict__ hLo,
    const int* __restrict__ batch,
    float* __restrict__ psum, float* __restrict__ pcnt)
{
    const int tid = threadIdx.x;
    const int tx = tid & 31;
    const int ty = tid >> 5;
    const int n0 = blockIdx.x * 64;
    const int d0 = tx * 4;

    float4 acc = make_float4(0.f, 0.f, 0.f, 0.f);
    int cur = -1, crun = 0;
#pragma unroll
    for (int it = 0; it < 8; ++it) {
        int n = n0 + it * 8 + ty;
        if (n < N_NODES) {
            int g = batch[n];
            if (g != cur) {
                if (cur >= 0) {
                    atomicAdd(&psum[cur * 128 + d0 + 0], acc.x);
                    atomicAdd(&psum[cur * 128 + d0 + 1], acc.y);
                    atomicAdd(&psum[cur * 128 + d0 + 2], acc.z);
                    atomicAdd(&psum[cur * 128 + d0 + 3], acc.w);
                    if (tx == 0) atomicAdd(&pcnt[cur], (float)crun);
                }
                cur = g; acc = make_float4(0.f, 0.f, 0.f, 0.f); crun = 0;
            }
            ushort4 h = *(const ushort4*)(hHi + (size_t)n * 128 + d0);
            ushort4 l = *(const ushort4*)(hLo + (size_t)n * 128 + d0);
            acc.x += bjoin(h.x, l.x);
            acc.y += bjoin(h.y, l.y);
            acc.z += bjoin(h.z, l.z);
            acc.w += bjoin(h.w, l.w);
            crun++;
        }
    }
    if (cur >= 0) {
        atomicAdd(&psum[cur * 128 + d0 + 0], acc.x);
        atomicAdd(&psum[cur * 128 + d0 + 1], acc.y);
        atomicAdd(&psum[cur * 128 + d0 + 2], acc.z);
        atomicAdd(&psum[cur * 128 + d0 + 3], acc.w);
        if (tx == 0) atomicAdd(&pcnt[cur], (float)crun);
    }
}

// ---------------------------------------------------------------- head
__global__ __launch_bounds__(256) void k_head(
    const float* __restrict__ psum, const float* __restrict__ pcnt,
    const float* __restrict__ Wlin, const float* __restrict__ blin,
    float* __restrict__ out)
{
    int g = blockIdx.x * 4 + (threadIdx.x >> 6);
    if (g >= N_GRAPH) return;
    int lane = threadIdx.x & 63;
    float c = fmaxf(pcnt[g], 1.f);
    float2 s = *(const float2*)(psum + (size_t)g * 128 + lane * 2);
    float p = (s.x * Wlin[lane * 2] + s.y * Wlin[lane * 2 + 1]) / c;
#pragma unroll
    for (int off = 32; off > 0; off >>= 1) p += __shfl_xor(p, off);
    if (lane == 0) out[g] = p + blin[0];
}

// ---------------------------------------------------------------- launch
extern "C" void kernel_launch(void* const* d_in, const int* in_sizes, int n_in,
                              void* d_out, int out_size, void* d_ws, size_t ws_size,
                              hipStream_t stream) {
    const float* x     = (const float*)d_in[0];
    const int*   ei    = (const int*)d_in[1];
    const int*   batch = (const int*)d_in[3];
    const float* Wl1 = (const float*)d_in[4],  *bl1 = (const float*)d_in[5];
    const float* Wr1 = (const float*)d_in[6],  *br1 = (const float*)d_in[7];
    const float* att1= (const float*)d_in[8],  *b1  = (const float*)d_in[9];
    const float* Wl2 = (const float*)d_in[10], *bl2 = (const float*)d_in[11];
    const float* Wr2 = (const float*)d_in[12], *br2 = (const float*)d_in[13];
    const float* att2= (const float*)d_in[14], *b2  = (const float*)d_in[15];
    const float* Wlin= (const float*)d_in[16], *blin= (const float*)d_in[17];
    float* out = (float*)d_out;

    const int* src = ei;
    const int* dst = ei + N_EDGES;

    char* p = (char*)d_ws;
    auto carve = [&](size_t bytes) {
        void* r = (void*)p;
        p += (bytes + 255) & ~(size_t)255;
        return r;
    };
    unsigned short* bufA   = (unsigned short*)carve((size_t)N_NODES * 128 * 2); // xl fp16
    unsigned short* bufB   = (unsigned short*)carve((size_t)N_NODES * 128 * 2); // xr fp16
    unsigned short* Hhi    = (unsigned short*)carve((size_t)N_NODES * 128 * 2);
    unsigned short* Hlo    = (unsigned short*)carve((size_t)N_NODES * 128 * 2);
    unsigned short* Xhi1   = (unsigned short*)carve((size_t)N_NODES * 64 * 2);
    unsigned short* Xlo1   = (unsigned short*)carve((size_t)N_NODES * 64 * 2);
    unsigned short* WThi   = (unsigned short*)carve(49152 * 2);
    unsigned short* WTlo   = (unsigned short*)carve(49152 * 2);
    int*            offsets= (int*)carve((size_t)(N_NODES + 1) * 4);
    int*            rank   = (int*)carve((size_t)N_EDGES * 4);
    int*            partials=(int*)carve(256 * 4);
    int*            col_src= (int*)carve((size_t)N_EDGES * 4);
    // zero region: counts (padded: 1 counter / 64B line) | psum | pcnt
    const size_t counts_bytes = (size_t)N_NODES * 64;   // 3.2 MB
    char* zb = (char*)carve(counts_bytes + 262144 + 2048);
    int*   counts = (int*)zb;
    float* psum   = (float*)(zb + counts_bytes);
    float* pcnt   = (float*)(zb + counts_bytes + 262144);
    const size_t zbytes = counts_bytes + 262144 + 2048;

    hipMemsetAsync(zb, 0, zbytes, stream);

    // prepX + prepW (fast, HBM-bound)
    k_prep<<<NB_PX + NB_PW, 256, 0, stream>>>(
        x, Wl1, Wr1, Wl2, Wr2, Xhi1, Xlo1, WThi, WTlo);

    // layer-1 GEMM (K=64) fused with dst-histogram (hist hides under MFMA)
    k_gemm1_hist<<<GB_GEMM + GB_HIST, 256, 0, stream>>>(
        Xhi1, Xlo1, WThi, WTlo, bl1, br1, bufA, bufB, F_IN,
        dst, counts, rank);

    k_scan1<<<SCAN_NB, 256, 0, stream>>>(counts, offsets, partials);
    k_scan3<<<SCAN_NB, 256, 0, stream>>>(offsets, partials);
    k_fill <<<(N_EDGES + 255) / 256, 256, 0, stream>>>(src, dst, offsets, rank, col_src);

    k_edge<<<(N_NODES + 3) / 4, 256, 0, stream>>>(
        bufA, bufB, att1, b1, offsets, col_src, Hhi, Hlo);
    // layer 2 (K=128)
    k_gemm_mfma<<<GB_GEMM, 256, 0, stream>>>(Hhi, Hlo, WThi + 16384, WTlo + 16384,
                                             bl2, br2, bufA, bufB, H_DIM);
    k_edge<<<(N_NODES + 3) / 4, 256, 0, stream>>>(
        bufA, bufB, att2, b2, offsets, col_src, Hhi, Hlo);
    // pool + head
    k_pool<<<(N_NODES + 63) / 64, 256, 0, stream>>>(Hhi, Hlo, batch, psum, pcnt);
    k_head<<<(N_GRAPH + 3) / 4, 256, 0, stream>>>(psum, pcnt, Wlin, blin, out);
}

// Round 3
// 286.560 us; speedup vs baseline: 1.0923x; 1.0451x over previous
//
#include <hip/hip_runtime.h>
#include <hip/hip_fp16.h>
#include <math.h>

#define N_NODES 50000
#define N_EDGES 800000
#define F_IN    64
#define H_DIM   128
#define N_GRAPH 512
#define NEG_SLOPE 0.2f

typedef __attribute__((ext_vector_type(8))) short short8;   // 8 bf16 (4 VGPRs)
typedef __attribute__((ext_vector_type(4))) float f32x4;
typedef __attribute__((ext_vector_type(2))) float f32x2;

// ---- counting-sort geometry: bins of 256 dst nodes, 2048-edge bin1 blocks
#define NBIN   196                      // ceil(50000/256)
#define NBLK1  391                      // ceil(800000/2048)
#define NBB    (NBIN * NBLK1)           // 76636 (bin-major count matrix)
#define SCANA_NB ((NBB + 255) / 256)    // 300

// fp32 -> bf16(hi) + bf16(lo), truncation split (residual ~2^-16 relative)
__device__ __forceinline__ void bsplit(float v, unsigned short& h, unsigned short& l) {
    unsigned u = __float_as_uint(v);
    h = (unsigned short)(u >> 16);
    float hf = __uint_as_float(u & 0xFFFF0000u);
    float r = v - hf;
    l = (unsigned short)(__float_as_uint(r) >> 16);
}
__device__ __forceinline__ float bjoin(unsigned short h, unsigned short l) {
    return __uint_as_float(((unsigned)h) << 16) + __uint_as_float(((unsigned)l) << 16);
}

// ------------------- fused prep: prepX | prepW(frag-major swizzle) | bin1
// bin1: LDS histogram over 196 coarse bins (dst>>8); per-edge local rank via
// LDS atomic (fast); per-(bin,block) counts to global. ZERO global atomics —
// replaces the 800k device-scope fetch-adds that were ~45us of atomic limbo.
#define NB_PX 3125
#define NB_PW 192
__global__ __launch_bounds__(256) void k_prep(
    const float* __restrict__ x,
    const float* __restrict__ Wl1, const float* __restrict__ Wr1,
    const float* __restrict__ Wl2, const float* __restrict__ Wr2,
    const int* __restrict__ dst,
    unsigned short* __restrict__ Xhi, unsigned short* __restrict__ Xlo,
    unsigned short* __restrict__ WThi, unsigned short* __restrict__ WTlo,
    int* __restrict__ lrank, int* __restrict__ bcnt)
{
    __shared__ int cnt_lds[NBIN];
    const int bid = blockIdx.x, tid = threadIdx.x;
    if (bid < NB_PX) {
        int i4 = (bid * 256 + tid) * 4;
        if (i4 < N_NODES * F_IN) {
            float4 v = *(const float4*)(x + i4);
            ushort4 h, l;
            bsplit(v.x, h.x, l.x); bsplit(v.y, h.y, l.y);
            bsplit(v.z, h.z, l.z); bsplit(v.w, h.w, l.w);
            *(ushort4*)(Xhi + i4) = h;
            *(ushort4*)(Xlo + i4) = l;
        }
    } else if (bid < NB_PX + NB_PW) {
        int idx = (bid - NB_PX) * 256 + tid;   // 0..49151
        if (idx < 49152) {
            const float* W; int K, li, base, o;
            if (idx < 8192)       { W = Wl1; K = 64;  li = idx;         base = 0;     o = 0; }
            else if (idx < 16384) { W = Wr1; K = 64;  li = idx - 8192;  base = 0;     o = 1; }
            else if (idx < 32768) { W = Wl2; K = 128; li = idx - 16384; base = 16384; o = 0; }
            else                  { W = Wr2; K = 128; li = idx - 32768; base = 16384; o = 1; }
            int c = li / K, k = li - c * K;
            int g = c >> 4, n16 = c & 15;
            int kkblk = k >> 5, quad = (k >> 3) & 3, j = k & 7;
            int off = base + kkblk * 8192 + o * 4096 + g * 512 + (quad * 16 + n16) * 8 + j;
            unsigned short h, l;
            bsplit(W[k * 128 + c], h, l);
            WThi[off] = h; WTlo[off] = l;
        }
    } else {
        const int b2 = bid - NB_PX - NB_PW;    // 0..390
        if (tid < NBIN) cnt_lds[tid] = 0;
        __syncthreads();
#pragma unroll
        for (int it = 0; it < 8; ++it) {
            int e = b2 * 2048 + it * 256 + tid;
            if (e < N_EDGES) {
                int d = dst[e];
                lrank[e] = atomicAdd(&cnt_lds[d >> 8], 1);
            }
        }
        __syncthreads();
        if (tid < NBIN) bcnt[tid * NBLK1 + b2] = cnt_lds[tid];
    }
}

// ---------------------------------------------------------------- scans
// flat exclusive scan of bcnt[NBB] (bin-major) -> bbase
__global__ __launch_bounds__(256) void k_scanA(const int* __restrict__ bcnt,
                                               int* __restrict__ bbase,
                                               int* __restrict__ partials) {
    __shared__ int s[256];
    int t = threadIdx.x, gid = blockIdx.x * 256 + t;
    int v = (gid < NBB) ? bcnt[gid] : 0;
    s[t] = v;
    __syncthreads();
    for (int off = 1; off < 256; off <<= 1) {
        int x = (t >= off) ? s[t - off] : 0;
        __syncthreads();
        s[t] += x;
        __syncthreads();
    }
    if (gid < NBB) bbase[gid] = s[t] - v;
    if (t == 255) partials[blockIdx.x] = s[t];
}

__global__ __launch_bounds__(256) void k_scanB(int* __restrict__ bbase,
                                               const int* __restrict__ partials) {
    __shared__ int red[256];
    const int t = threadIdx.x, b = blockIdx.x;
    int acc = 0;
    for (int j = t; j < b; j += 256) acc += partials[j];
    red[t] = acc;
    __syncthreads();
    for (int off = 128; off > 0; off >>= 1) {
        if (t < off) red[t] += red[t + off];
        __syncthreads();
    }
    int base = red[0];
    int gid = b * 256 + t;
    if (gid < NBB) bbase[gid] += base;
}

// scatter edges into bin-sorted order; pack src (16b) | dst&255 (8b)
__global__ __launch_bounds__(256) void k_bin2(const int* __restrict__ src,
                                              const int* __restrict__ dst,
                                              const int* __restrict__ lrank,
                                              const int* __restrict__ bbase,
                                              unsigned* __restrict__ ebin) {
    int e = blockIdx.x * 256 + threadIdx.x;
    if (e < N_EDGES) {
        int d = dst[e];
        int pos = bbase[(d >> 8) * NBLK1 + (e >> 11)] + lrank[e];
        ebin[pos] = (unsigned)src[e] | ((unsigned)(d & 255) << 16);
    }
}

// per-bin: exact per-node counts (LDS) -> in-bin scan -> offsets + col_src.
// offsets[d] = binEdgeBase + in-bin prefix (global node scan eliminated).
__global__ __launch_bounds__(256) void k_bin3(const unsigned* __restrict__ ebin,
                                              const int* __restrict__ bbase,
                                              int* __restrict__ offsets,
                                              int* __restrict__ col_src) {
    __shared__ int cnt2[256];
    __shared__ int sc[256];
    __shared__ int cur[256];
    const int b = blockIdx.x, t = threadIdx.x;
    const int lo = bbase[b * NBLK1];
    const int hi = (b == NBIN - 1) ? N_EDGES : bbase[(b + 1) * NBLK1];

    cnt2[t] = 0;
    __syncthreads();
    for (int pos = lo + t; pos < hi; pos += 256) {
        unsigned u = ebin[pos];
        atomicAdd(&cnt2[u >> 16], 1);
    }
    __syncthreads();
    int v = cnt2[t];
    sc[t] = v;
    __syncthreads();
    for (int off = 1; off < 256; off <<= 1) {
        int x = (t >= off) ? sc[t - off] : 0;
        __syncthreads();
        sc[t] += x;
        __syncthreads();
    }
    int myoff = lo + sc[t] - v;            // exclusive in-bin prefix + bin base
    int node = b * 256 + t;
    if (node < N_NODES) offsets[node] = myoff;
    cur[t] = myoff;
    if (b == NBIN - 1 && t == 0) offsets[N_NODES] = N_EDGES;
    __syncthreads();
    for (int pos = lo + t; pos < hi; pos += 256) {
        unsigned u = ebin[pos];
        int p = atomicAdd(&cur[u >> 16], 1);
        col_src[p] = (int)(u & 0xFFFFu);
    }
}

// ---------------------------------------------------------------- MFMA GEMM
// R15-proven: 3-pass bf16-split, 64-row blocks, per-kk staged X tile,
// B-frags direct from fragment-major swizzled W. Output FP16.
#define APITCH 40
#define GB_GEMM ((N_NODES + 63) / 64)   // 782
__global__ __launch_bounds__(256, 4) void k_gemm_mfma(
    const unsigned short* __restrict__ Xhi, const unsigned short* __restrict__ Xlo,
    const unsigned short* __restrict__ WThi, const unsigned short* __restrict__ WTlo,
    const float* __restrict__ bl, const float* __restrict__ br,
    unsigned short* __restrict__ OL, unsigned short* __restrict__ OR_, int K)
{
    __shared__ __align__(16) unsigned short Ah[64 * APITCH];
    __shared__ __align__(16) unsigned short Al[64 * APITCH];

    const int tid  = threadIdx.x;
    const int wv   = tid >> 6;        // wave: cols [wv*32, wv*32+32)
    const int lane = tid & 63;
    const int n16  = lane & 15;
    const int quad = lane >> 4;
    const int row0 = blockIdx.x * 64;

    f32x4 acc[4][2][2];               // [rtile][ctile][out]
#pragma unroll
    for (int r = 0; r < 4; ++r)
#pragma unroll
        for (int c = 0; c < 2; ++c)
#pragma unroll
            for (int o = 0; o < 2; ++o) acc[r][c][o] = (f32x4)0.f;

    for (int kk = 0; kk < K; kk += 32) {
        // stage X tile: 64 rows x 32 k, hi+lo. 512 chunks of 16B.
#pragma unroll
        for (int jj = 0; jj < 2; ++jj) {
            int j = tid + jj * 256;
            int part = j >> 8;
            int r = (j & 255) >> 2, sub = j & 3;
            int grow = row0 + r;
            const unsigned short* s = (part ? Xlo : Xhi) + (size_t)grow * K + kk + sub * 8;
            unsigned short* dl = (part ? Al : Ah) + r * APITCH + sub * 8;
            uint4 v = make_uint4(0u, 0u, 0u, 0u);
            if (grow < N_NODES) v = *(const uint4*)s;
            *(uint4*)dl = v;
        }
        __syncthreads();

        // B frags direct from swizzled global (coalesced: lane*8 shorts)
        const unsigned short* wb_h = WThi + (size_t)(kk >> 5) * 8192;
        const unsigned short* wb_l = WTlo + (size_t)(kk >> 5) * 8192;
        short8 bh[2][2], bo[2][2];
#pragma unroll
        for (int c = 0; c < 2; ++c)
#pragma unroll
            for (int o = 0; o < 2; ++o) {
                size_t off = (size_t)o * 4096 + (size_t)(wv * 2 + c) * 512 + (size_t)lane * 8;
                bh[c][o] = *(const short8*)(wb_h + off);
                bo[c][o] = *(const short8*)(wb_l + off);
            }
#pragma unroll
        for (int r = 0; r < 4; ++r) {
            int rl = r * 16 + n16;
            short8 ah = *(const short8*)(Ah + rl * APITCH + quad * 8);
            short8 al = *(const short8*)(Al + rl * APITCH + quad * 8);
#pragma unroll
            for (int c = 0; c < 2; ++c)
#pragma unroll
                for (int o = 0; o < 2; ++o) {
                    f32x4 t = acc[r][c][o];
                    t = __builtin_amdgcn_mfma_f32_16x16x32_bf16(ah, bh[c][o], t, 0, 0, 0);
                    t = __builtin_amdgcn_mfma_f32_16x16x32_bf16(ah, bo[c][o], t, 0, 0, 0);
                    t = __builtin_amdgcn_mfma_f32_16x16x32_bf16(al, bh[c][o], t, 0, 0, 0);
                    acc[r][c][o] = t;
                }
        }
        __syncthreads();
    }

    // epilogue: C/D layout col=lane&15, row=quad*4+reg; store fp16
#pragma unroll
    for (int r = 0; r < 4; ++r)
#pragma unroll
        for (int c = 0; c < 2; ++c)
#pragma unroll
            for (int o = 0; o < 2; ++o) {
                int col = wv * 32 + c * 16 + n16;
                float bb = (o ? br : bl)[col];
                unsigned short* O = o ? OR_ : OL;
#pragma unroll
                for (int g = 0; g < 4; ++g) {
                    int grow = row0 + r * 16 + quad * 4 + g;
                    if (grow < N_NODES) {
                        __half hv = __float2half(acc[r][c][o][g] + bb);
                        O[(size_t)grow * 128 + col] = *(unsigned short*)&hv;
                    }
                }
            }
}

// ---------------------------------------------------------------- edge phase
// 16-lane butterfly sum on the VALU pipe via DPP (no ds_swizzle / lgkmcnt).
__device__ __forceinline__ float red16dpp(float v) {
    v += __int_as_float(__builtin_amdgcn_update_dpp(
             0, __float_as_int(v), 0xB1, 0xF, 0xF, true));   // quad_perm [1,0,3,2]
    v += __int_as_float(__builtin_amdgcn_update_dpp(
             0, __float_as_int(v), 0x4E, 0xF, 0xF, true));   // quad_perm [2,3,0,1]
    v += __int_as_float(__builtin_amdgcn_update_dpp(
             0, __float_as_int(v), 0x141, 0xF, 0xF, true));  // row_half_mirror
    v += __int_as_float(__builtin_amdgcn_update_dpp(
             0, __float_as_int(v), 0x140, 0xF, 0xF, true));  // row_mirror
    return v;
}

// load 8 fp16 (16B) -> four f32x2 (packed-f32 friendly)
__device__ __forceinline__ void load_h8v(const unsigned short* base, size_t off,
                                         f32x2 x[4]) {
    uint4 u = *(const uint4*)(base + off);
    float2 a = __half22float2(*(__half2*)&u.x);
    float2 b = __half22float2(*(__half2*)&u.y);
    float2 c = __half22float2(*(__half2*)&u.z);
    float2 d = __half22float2(*(__half2*)&u.w);
    f32x2 v0 = {a.x, a.y}; x[0] = v0;
    f32x2 v1 = {b.x, b.y}; x[1] = v1;
    f32x2 v2 = {c.x, c.y}; x[2] = v2;
    f32x2 v3 = {d.x, d.y}; x[3] = v3;
}

// att . leaky_relu(x + r) over this lane's 8 dims, packed f32x2.
__device__ __forceinline__ float dot8lk(const f32x2 x[4], const f32x2 r[4],
                                        const f32x2 a[4]) {
    f32x2 e0 = x[0] + r[0];
    f32x2 e1 = x[1] + r[1];
    f32x2 l0 = __builtin_elementwise_max(e0, NEG_SLOPE * e0);
    f32x2 l1 = __builtin_elementwise_max(e1, NEG_SLOPE * e1);
    f32x2 s0 = a[0] * l0;
    f32x2 s1 = a[1] * l1;
    f32x2 e2 = x[2] + r[2];
    f32x2 e3 = x[3] + r[3];
    f32x2 l2 = __builtin_elementwise_max(e2, NEG_SLOPE * e2);
    f32x2 l3 = __builtin_elementwise_max(e3, NEG_SLOPE * e3);
    s0 += a[2] * l2;
    s1 += a[3] * l3;
    f32x2 s = s0 + s1;
    return s.x + s.y;
}

// One wave per destination node; 4 quarters of 16 lanes each process a
// different incoming edge. Packed f32, DPP reduce, deferred-max softmax.
__global__ __launch_bounds__(256) void k_edge(
    const unsigned short* __restrict__ xl, const unsigned short* __restrict__ xr,
    const float* __restrict__ att, const float* __restrict__ bias,
    const int* __restrict__ offsets, const int* __restrict__ col_src,
    unsigned short* __restrict__ outHi, unsigned short* __restrict__ outLo)
{
    int d = blockIdx.x * 4 + (threadIdx.x >> 6);
    if (d >= N_NODES) return;
    const int lane = threadIdx.x & 63;
    const int q = lane >> 4;
    const int t = lane & 15;
    const size_t dim0 = (size_t)t * 8;

    f32x2 rr[4], aa[4], xs[4];
    load_h8v(xr, (size_t)d * 128 + dim0, rr);
    {
        const float4 a0 = *(const float4*)(att + dim0);
        const float4 a1 = *(const float4*)(att + dim0 + 4);
        f32x2 w0 = {a0.x, a0.y}; aa[0] = w0;
        f32x2 w1 = {a0.z, a0.w}; aa[1] = w1;
        f32x2 w2 = {a1.x, a1.y}; aa[2] = w2;
        f32x2 w3 = {a1.z, a1.w}; aa[3] = w3;
    }
    load_h8v(xl, (size_t)d * 128 + dim0, xs);
    float sl = red16dpp(dot8lk(xs, rr, aa));   // identical in all 64 lanes

    // deferred-max online softmax: m is a reference >= logit-8 for all
    // accumulated terms; every quarter starts at the self-loop logit.
    float m = sl, thr = sl + 8.f;
    float lsum = (q == 0) ? 1.f : 0.f;
    f32x2 zero = {0.f, 0.f};
    f32x2 acc[4];
#pragma unroll
    for (int j = 0; j < 4; ++j) acc[j] = (q == 0) ? xs[j] : zero;

    const int ibeg = offsets[d], iend = offsets[d + 1];
    for (int base = ibeg; base < iend; base += 4) {
        int i = base + q;
        bool valid = (i < iend);
        int s = valid ? col_src[i] : d;      // pad with self row: logit=sl<=m, w zeroed
        f32x2 x[4];
        load_h8v(xl, (size_t)s * 128 + dim0, x);
        float logit = red16dpp(dot8lk(x, rr, aa));   // quarter-uniform
        if (__builtin_expect(logit > thr, 0)) {      // rare rescale path
            float sc = __expf(m - logit);
            lsum *= sc;
#pragma unroll
            for (int j = 0; j < 4; ++j) acc[j] = acc[j] * sc;
            m = logit; thr = logit + 8.f;
        }
        float w = valid ? __expf(logit - m) : 0.f;   // <= e^8
        lsum += w;
        f32x2 w2 = {w, w};
#pragma unroll
        for (int j = 0; j < 4; ++j) acc[j] += w2 * x[j];   // pk_fma
    }

    // merge the 4 quarters (each holds partials relative to its own m)
    float M = m;
    M = fmaxf(M, __shfl_xor(M, 16));
    M = fmaxf(M, __shfl_xor(M, 32));
    float sc = __expf(m - M);
    lsum *= sc;
    f32x2 sc2 = {sc, sc};
#pragma unroll
    for (int j = 0; j < 4; ++j) acc[j] = acc[j] * sc2;
#pragma unroll
    for (int off = 16; off <= 32; off <<= 1) {
        lsum += __shfl_xor(lsum, off);
#pragma unroll
        for (int j = 0; j < 4; ++j) {
            acc[j].x += __shfl_xor(acc[j].x, off);
            acc[j].y += __shfl_xor(acc[j].y, off);
        }
    }

    if (q == 0) {
        float inv = 1.f / lsum;
        const float4 b0 = *(const float4*)(bias + dim0);
        const float4 b1 = *(const float4*)(bias + dim0 + 4);
        float bv[8] = {b0.x, b0.y, b0.z, b0.w, b1.x, b1.y, b1.z, b1.w};
        float v[8];
#pragma unroll
        for (int j = 0; j < 4; ++j) {
            v[2 * j]     = fmaxf(fmaf(acc[j].x, inv, bv[2 * j]), 0.f);
            v[2 * j + 1] = fmaxf(fmaf(acc[j].y, inv, bv[2 * j + 1]), 0.f);
        }
        union { unsigned short s[8]; uint4 u; } Hh, Ll;
#pragma unroll
        for (int i2 = 0; i2 < 8; ++i2) bsplit(v[i2], Hh.s[i2], Ll.s[i2]);
        *(uint4*)(outHi + (size_t)d * 128 + dim0) = Hh.u;
        *(uint4*)(outLo + (size_t)d * 128 + dim0) = Ll.u;
    }
}

// ---------------------------------------------------------------- pooling
__global__ __launch_bounds__(256) void k_pool(
    const unsigned short* __restrict__ hHi, const unsigned short* __restrict__ hLo,
    const int* __restrict__ batch,
    float* __restrict__ psum, float* __restrict__ pcnt)
{
    const int tid = threadIdx.x;
    const int tx = tid & 31;
    const int ty = tid >> 5;
    const int n0 = blockIdx.x * 64;
    const int d0 = tx * 4;

    float4 acc = make_float4(0.f, 0.f, 0.f, 0.f);
    int cur = -1, crun = 0;
#pragma unroll
    for (int it = 0; it < 8; ++it) {
        int n = n0 + it * 8 + ty;
        if (n < N_NODES) {
            int g = batch[n];
            if (g != cur) {
                if (cur >= 0) {
                    atomicAdd(&psum[cur * 128 + d0 + 0], acc.x);
                    atomicAdd(&psum[cur * 128 + d0 + 1], acc.y);
                    atomicAdd(&psum[cur * 128 + d0 + 2], acc.z);
                    atomicAdd(&psum[cur * 128 + d0 + 3], acc.w);
                    if (tx == 0) atomicAdd(&pcnt[cur], (float)crun);
                }
                cur = g; acc = make_float4(0.f, 0.f, 0.f, 0.f); crun = 0;
            }
            ushort4 h = *(const ushort4*)(hHi + (size_t)n * 128 + d0);
            ushort4 l = *(const ushort4*)(hLo + (size_t)n * 128 + d0);
            acc.x += bjoin(h.x, l.x);
            acc.y += bjoin(h.y, l.y);
            acc.z += bjoin(h.z, l.z);
            acc.w += bjoin(h.w, l.w);
            crun++;
        }
    }
    if (cur >= 0) {
        atomicAdd(&psum[cur * 128 + d0 + 0], acc.x);
        atomicAdd(&psum[cur * 128 + d0 + 1], acc.y);
        atomicAdd(&psum[cur * 128 + d0 + 2], acc.z);
        atomicAdd(&psum[cur * 128 + d0 + 3], acc.w);
        if (tx == 0) atomicAdd(&pcnt[cur], (float)crun);
    }
}

// ---------------------------------------------------------------- head
__global__ __launch_bounds__(256) void k_head(
    const float* __restrict__ psum, const float* __restrict__ pcnt,
    const float* __restrict__ Wlin, const float* __restrict__ blin,
    float* __restrict__ out)
{
    int g = blockIdx.x * 4 + (threadIdx.x >> 6);
    if (g >= N_GRAPH) return;
    int lane = threadIdx.x & 63;
    float c = fmaxf(pcnt[g], 1.f);
    float2 s = *(const float2*)(psum + (size_t)g * 128 + lane * 2);
    float p = (s.x * Wlin[lane * 2] + s.y * Wlin[lane * 2 + 1]) / c;
#pragma unroll
    for (int off = 32; off > 0; off >>= 1) p += __shfl_xor(p, off);
    if (lane == 0) out[g] = p + blin[0];
}

// ---------------------------------------------------------------- launch
extern "C" void kernel_launch(void* const* d_in, const int* in_sizes, int n_in,
                              void* d_out, int out_size, void* d_ws, size_t ws_size,
                              hipStream_t stream) {
    const float* x     = (const float*)d_in[0];
    const int*   ei    = (const int*)d_in[1];
    const int*   batch = (const int*)d_in[3];
    const float* Wl1 = (const float*)d_in[4],  *bl1 = (const float*)d_in[5];
    const float* Wr1 = (const float*)d_in[6],  *br1 = (const float*)d_in[7];
    const float* att1= (const float*)d_in[8],  *b1  = (const float*)d_in[9];
    const float* Wl2 = (const float*)d_in[10], *bl2 = (const float*)d_in[11];
    const float* Wr2 = (const float*)d_in[12], *br2 = (const float*)d_in[13];
    const float* att2= (const float*)d_in[14], *b2  = (const float*)d_in[15];
    const float* Wlin= (const float*)d_in[16], *blin= (const float*)d_in[17];
    float* out = (float*)d_out;

    const int* src = ei;
    const int* dst = ei + N_EDGES;

    char* p = (char*)d_ws;
    auto carve = [&](size_t bytes) {
        void* r = (void*)p;
        p += (bytes + 255) & ~(size_t)255;
        return r;
    };
    unsigned short* bufA   = (unsigned short*)carve((size_t)N_NODES * 128 * 2); // xl fp16
    unsigned short* bufB   = (unsigned short*)carve((size_t)N_NODES * 128 * 2); // xr fp16
    unsigned short* Hhi    = (unsigned short*)carve((size_t)N_NODES * 128 * 2);
    unsigned short* Hlo    = (unsigned short*)carve((size_t)N_NODES * 128 * 2);
    unsigned short* Xhi1   = (unsigned short*)carve((size_t)N_NODES * 64 * 2);
    unsigned short* Xlo1   = (unsigned short*)carve((size_t)N_NODES * 64 * 2);
    unsigned short* WThi   = (unsigned short*)carve(49152 * 2);
    unsigned short* WTlo   = (unsigned short*)carve(49152 * 2);
    int*            offsets= (int*)carve((size_t)(N_NODES + 1) * 4);
    int*            lrank  = (int*)carve((size_t)N_EDGES * 4);
    int*            bcnt   = (int*)carve((size_t)NBB * 4);
    int*            bbase  = (int*)carve((size_t)NBB * 4);
    int*            partials=(int*)carve(SCANA_NB * 4);
    unsigned*       ebin   = (unsigned*)carve((size_t)N_EDGES * 4);
    int*            col_src= (int*)carve((size_t)N_EDGES * 4);
    // zero region: psum | pcnt
    char* zb = (char*)carve(262144 + 2048);
    float* psum   = (float*)zb;
    float* pcnt   = (float*)(zb + 262144);
    const size_t zbytes = 262144 + 2048;

    hipMemsetAsync(zb, 0, zbytes, stream);

    // prepX + prepW + bin1 (LDS histogram, no global atomics)
    k_prep<<<NB_PX + NB_PW + NBLK1, 256, 0, stream>>>(
        x, Wl1, Wr1, Wl2, Wr2, dst,
        Xhi1, Xlo1, WThi, WTlo, lrank, bcnt);

    // layer-1 GEMM (independent of CSR build)
    k_gemm_mfma<<<GB_GEMM, 256, 0, stream>>>(Xhi1, Xlo1, WThi, WTlo,
                                             bl1, br1, bufA, bufB, F_IN);

    // CSR build: scan bcnt -> scatter to bin-sorted -> per-bin offsets+fill
    k_scanA<<<SCANA_NB, 256, 0, stream>>>(bcnt, bbase, partials);
    k_scanB<<<SCANA_NB, 256, 0, stream>>>(bbase, partials);
    k_bin2 <<<(N_EDGES + 255) / 256, 256, 0, stream>>>(src, dst, lrank, bbase, ebin);
    k_bin3 <<<NBIN, 256, 0, stream>>>(ebin, bbase, offsets, col_src);

    k_edge<<<(N_NODES + 3) / 4, 256, 0, stream>>>(
        bufA, bufB, att1, b1, offsets, col_src, Hhi, Hlo);
    // layer 2 (K=128)
    k_gemm_mfma<<<GB_GEMM, 256, 0, stream>>>(Hhi, Hlo, WThi + 16384, WTlo + 16384,
                                             bl2, br2, bufA, bufB, H_DIM);
    k_edge<<<(N_NODES + 3) / 4, 256, 0, stream>>>(
        bufA, bufB, att2, b2, offsets, col_src, Hhi, Hlo);
    // pool + head
    k_pool<<<(N_NODES + 63) / 64, 256, 0, stream>>>(Hhi, Hlo, batch, psum, pcnt);
    k_head<<<(N_GRAPH + 3) / 4, 256, 0, stream>>>(psum, pcnt, Wlin, blin, out);
}

// Round 4
// 270.055 us; speedup vs baseline: 1.1591x; 1.0611x over previous
//
#include <hip/hip_runtime.h>
#include <hip/hip_fp16.h>
#include <math.h>

#define N_NODES 50000
#define N_EDGES 800000
#define F_IN    64
#define H_DIM   128
#define N_GRAPH 512
#define NEG_SLOPE 0.2f

typedef __attribute__((ext_vector_type(8))) short short8;   // 8 bf16 (4 VGPRs)
typedef __attribute__((ext_vector_type(4))) float f32x4;
typedef __attribute__((ext_vector_type(2))) float f32x2;

// ---- counting-sort geometry: bins of 256 dst nodes, 2048-edge bin1 blocks
#define NBIN   196                      // ceil(50000/256)
#define NBLK1  391                      // ceil(800000/2048)
#define NBB    (NBIN * NBLK1)           // 76636 (bin-major count matrix)
#define SCANA_NB ((NBB + 255) / 256)    // 300

// fp32 -> bf16(hi) + bf16(lo), truncation split (residual ~2^-16 relative)
__device__ __forceinline__ void bsplit(float v, unsigned short& h, unsigned short& l) {
    unsigned u = __float_as_uint(v);
    h = (unsigned short)(u >> 16);
    float hf = __uint_as_float(u & 0xFFFF0000u);
    float r = v - hf;
    l = (unsigned short)(__float_as_uint(r) >> 16);
}
__device__ __forceinline__ float bjoin(unsigned short h, unsigned short l) {
    return __uint_as_float(((unsigned)h) << 16) + __uint_as_float(((unsigned)l) << 16);
}

// ------------------- prep: prepW(frag-major swizzle) | bin1 (LDS histogram)
// prepX eliminated: layer-1 GEMM stages directly from fp32 x with in-kernel
// bsplit (bit-identical hi/lo), saving ~38MB of HBM traffic.
#define NB_PW 192
__global__ __launch_bounds__(256) void k_prep(
    const float* __restrict__ Wl1, const float* __restrict__ Wr1,
    const float* __restrict__ Wl2, const float* __restrict__ Wr2,
    const int* __restrict__ dst,
    unsigned short* __restrict__ WThi, unsigned short* __restrict__ WTlo,
    int* __restrict__ lrank, int* __restrict__ bcnt)
{
    __shared__ int cnt_lds[NBIN];
    const int bid = blockIdx.x, tid = threadIdx.x;
    if (bid < NB_PW) {
        int idx = bid * 256 + tid;   // 0..49151
        if (idx < 49152) {
            const float* W; int K, li, base, o;
            if (idx < 8192)       { W = Wl1; K = 64;  li = idx;         base = 0;     o = 0; }
            else if (idx < 16384) { W = Wr1; K = 64;  li = idx - 8192;  base = 0;     o = 1; }
            else if (idx < 32768) { W = Wl2; K = 128; li = idx - 16384; base = 16384; o = 0; }
            else                  { W = Wr2; K = 128; li = idx - 32768; base = 16384; o = 1; }
            int c = li / K, k = li - c * K;
            int g = c >> 4, n16 = c & 15;
            int kkblk = k >> 5, quad = (k >> 3) & 3, j = k & 7;
            int off = base + kkblk * 8192 + o * 4096 + g * 512 + (quad * 16 + n16) * 8 + j;
            unsigned short h, l;
            bsplit(W[k * 128 + c], h, l);
            WThi[off] = h; WTlo[off] = l;
        }
    } else {
        const int b2 = bid - NB_PW;    // 0..390
        if (tid < NBIN) cnt_lds[tid] = 0;
        __syncthreads();
#pragma unroll
        for (int it = 0; it < 8; ++it) {
            int e = b2 * 2048 + it * 256 + tid;
            if (e < N_EDGES) {
                int d = dst[e];
                lrank[e] = atomicAdd(&cnt_lds[d >> 8], 1);
            }
        }
        __syncthreads();
        if (tid < NBIN) bcnt[tid * NBLK1 + b2] = cnt_lds[tid];
    }
}

// ---------------------------------------------------------------- scans
// flat exclusive scan of bcnt[NBB] (bin-major) -> bbase
__global__ __launch_bounds__(256) void k_scanA(const int* __restrict__ bcnt,
                                               int* __restrict__ bbase,
                                               int* __restrict__ partials) {
    __shared__ int s[256];
    int t = threadIdx.x, gid = blockIdx.x * 256 + t;
    int v = (gid < NBB) ? bcnt[gid] : 0;
    s[t] = v;
    __syncthreads();
    for (int off = 1; off < 256; off <<= 1) {
        int x = (t >= off) ? s[t - off] : 0;
        __syncthreads();
        s[t] += x;
        __syncthreads();
    }
    if (gid < NBB) bbase[gid] = s[t] - v;
    if (t == 255) partials[blockIdx.x] = s[t];
}

__global__ __launch_bounds__(256) void k_scanB(int* __restrict__ bbase,
                                               const int* __restrict__ partials) {
    __shared__ int red[256];
    const int t = threadIdx.x, b = blockIdx.x;
    int acc = 0;
    for (int j = t; j < b; j += 256) acc += partials[j];
    red[t] = acc;
    __syncthreads();
    for (int off = 128; off > 0; off >>= 1) {
        if (t < off) red[t] += red[t + off];
        __syncthreads();
    }
    int base = red[0];
    int gid = b * 256 + t;
    if (gid < NBB) bbase[gid] += base;
}

// scatter edges into bin-sorted order; pack src (16b) | dst&255 (8b)
__global__ __launch_bounds__(256) void k_bin2(const int* __restrict__ src,
                                              const int* __restrict__ dst,
                                              const int* __restrict__ lrank,
                                              const int* __restrict__ bbase,
                                              unsigned* __restrict__ ebin) {
    int e = blockIdx.x * 256 + threadIdx.x;
    if (e < N_EDGES) {
        int d = dst[e];
        int pos = bbase[(d >> 8) * NBLK1 + (e >> 11)] + lrank[e];
        ebin[pos] = (unsigned)src[e] | ((unsigned)(d & 255) << 16);
    }
}

// per-bin: exact per-node counts (LDS) -> in-bin scan -> offsets + col_src.
__global__ __launch_bounds__(256) void k_bin3(const unsigned* __restrict__ ebin,
                                              const int* __restrict__ bbase,
                                              int* __restrict__ offsets,
                                              int* __restrict__ col_src) {
    __shared__ int cnt2[256];
    __shared__ int sc[256];
    __shared__ int cur[256];
    const int b = blockIdx.x, t = threadIdx.x;
    const int lo = bbase[b * NBLK1];
    const int hi = (b == NBIN - 1) ? N_EDGES : bbase[(b + 1) * NBLK1];

    cnt2[t] = 0;
    __syncthreads();
    for (int pos = lo + t; pos < hi; pos += 256) {
        unsigned u = ebin[pos];
        atomicAdd(&cnt2[u >> 16], 1);
    }
    __syncthreads();
    int v = cnt2[t];
    sc[t] = v;
    __syncthreads();
    for (int off = 1; off < 256; off <<= 1) {
        int x = (t >= off) ? sc[t - off] : 0;
        __syncthreads();
        sc[t] += x;
        __syncthreads();
    }
    int myoff = lo + sc[t] - v;            // exclusive in-bin prefix + bin base
    int node = b * 256 + t;
    if (node < N_NODES) offsets[node] = myoff;
    cur[t] = myoff;
    if (b == NBIN - 1 && t == 0) offsets[N_NODES] = N_EDGES;
    __syncthreads();
    for (int pos = lo + t; pos < hi; pos += 256) {
        unsigned u = ebin[pos];
        int p = atomicAdd(&cur[u >> 16], 1);
        col_src[p] = (int)(u & 0xFFFFu);
    }
}

// ---------------------------------------------------------------- MFMA GEMM
// 3-pass bf16-split, 64-row blocks, per-kk staged X tile, B-frags direct
// from fragment-major swizzled W. Output FP16. Layer 1 stages straight
// from fp32 x (bsplit in-register, bit-identical to the old prepX path).
#define APITCH 40
#define GB_GEMM ((N_NODES + 63) / 64)   // 782

template <bool F32SRC>
__device__ __forceinline__ void gemm_body(
    unsigned short* __restrict__ Ah, unsigned short* __restrict__ Al,
    const float* __restrict__ Xf,
    const unsigned short* __restrict__ Xhi, const unsigned short* __restrict__ Xlo,
    const unsigned short* __restrict__ WThi, const unsigned short* __restrict__ WTlo,
    const float* __restrict__ bl, const float* __restrict__ br,
    unsigned short* __restrict__ OL, unsigned short* __restrict__ OR_,
    int K, int blk)
{
    const int tid  = threadIdx.x;
    const int wv   = tid >> 6;        // wave: cols [wv*32, wv*32+32)
    const int lane = tid & 63;
    const int n16  = lane & 15;
    const int quad = lane >> 4;
    const int row0 = blk * 64;

    f32x4 acc[4][2][2];               // [rtile][ctile][out]
#pragma unroll
    for (int r = 0; r < 4; ++r)
#pragma unroll
        for (int c = 0; c < 2; ++c)
#pragma unroll
            for (int o = 0; o < 2; ++o) acc[r][c][o] = (f32x4)0.f;

    for (int kk = 0; kk < K; kk += 32) {
        // stage X tile: 64 rows x 32 k, hi+lo.
        if (F32SRC) {
            // 256 jobs: each loads 8 fp32, bsplits, writes 16B hi + 16B lo
            int r = tid >> 2, sub = tid & 3;
            int grow = row0 + r;
            float4 v0 = make_float4(0.f, 0.f, 0.f, 0.f);
            float4 v1 = make_float4(0.f, 0.f, 0.f, 0.f);
            if (grow < N_NODES) {
                const float* s = Xf + (size_t)grow * K + kk + sub * 8;
                v0 = *(const float4*)s;
                v1 = *(const float4*)(s + 4);
            }
            union { unsigned short s[8]; uint4 u; } Hh, Ll;
            bsplit(v0.x, Hh.s[0], Ll.s[0]); bsplit(v0.y, Hh.s[1], Ll.s[1]);
            bsplit(v0.z, Hh.s[2], Ll.s[2]); bsplit(v0.w, Hh.s[3], Ll.s[3]);
            bsplit(v1.x, Hh.s[4], Ll.s[4]); bsplit(v1.y, Hh.s[5], Ll.s[5]);
            bsplit(v1.z, Hh.s[6], Ll.s[6]); bsplit(v1.w, Hh.s[7], Ll.s[7]);
            *(uint4*)(Ah + r * APITCH + sub * 8) = Hh.u;
            *(uint4*)(Al + r * APITCH + sub * 8) = Ll.u;
        } else {
            // 512 chunks of 16B over 2 iterations
#pragma unroll
            for (int jj = 0; jj < 2; ++jj) {
                int j = tid + jj * 256;
                int part = j >> 8;
                int r = (j & 255) >> 2, sub = j & 3;
                int grow = row0 + r;
                const unsigned short* s = (part ? Xlo : Xhi) + (size_t)grow * K + kk + sub * 8;
                unsigned short* dl = (part ? Al : Ah) + r * APITCH + sub * 8;
                uint4 v = make_uint4(0u, 0u, 0u, 0u);
                if (grow < N_NODES) v = *(const uint4*)s;
                *(uint4*)dl = v;
            }
        }
        __syncthreads();

        // B frags direct from swizzled global (coalesced: lane*8 shorts)
        const unsigned short* wb_h = WThi + (size_t)(kk >> 5) * 8192;
        const unsigned short* wb_l = WTlo + (size_t)(kk >> 5) * 8192;
        short8 bh[2][2], bo[2][2];
#pragma unroll
        for (int c = 0; c < 2; ++c)
#pragma unroll
            for (int o = 0; o < 2; ++o) {
                size_t off = (size_t)o * 4096 + (size_t)(wv * 2 + c) * 512 + (size_t)lane * 8;
                bh[c][o] = *(const short8*)(wb_h + off);
                bo[c][o] = *(const short8*)(wb_l + off);
            }
#pragma unroll
        for (int r = 0; r < 4; ++r) {
            int rl = r * 16 + n16;
            short8 ah = *(const short8*)(Ah + rl * APITCH + quad * 8);
            short8 al = *(const short8*)(Al + rl * APITCH + quad * 8);
#pragma unroll
            for (int c = 0; c < 2; ++c)
#pragma unroll
                for (int o = 0; o < 2; ++o) {
                    f32x4 t = acc[r][c][o];
                    t = __builtin_amdgcn_mfma_f32_16x16x32_bf16(ah, bh[c][o], t, 0, 0, 0);
                    t = __builtin_amdgcn_mfma_f32_16x16x32_bf16(ah, bo[c][o], t, 0, 0, 0);
                    t = __builtin_amdgcn_mfma_f32_16x16x32_bf16(al, bh[c][o], t, 0, 0, 0);
                    acc[r][c][o] = t;
                }
        }
        __syncthreads();
    }

    // epilogue: C/D layout col=lane&15, row=quad*4+reg; store fp16
#pragma unroll
    for (int r = 0; r < 4; ++r)
#pragma unroll
        for (int c = 0; c < 2; ++c)
#pragma unroll
            for (int o = 0; o < 2; ++o) {
                int col = wv * 32 + c * 16 + n16;
                float bb = (o ? br : bl)[col];
                unsigned short* O = o ? OR_ : OL;
#pragma unroll
                for (int g = 0; g < 4; ++g) {
                    int grow = row0 + r * 16 + quad * 4 + g;
                    if (grow < N_NODES) {
                        __half hv = __float2half(acc[r][c][o][g] + bb);
                        O[(size_t)grow * 128 + col] = *(unsigned short*)&hv;
                    }
                }
            }
}

__global__ __launch_bounds__(256, 4) void k_gemm_f32(
    const float* __restrict__ Xf,
    const unsigned short* __restrict__ WThi, const unsigned short* __restrict__ WTlo,
    const float* __restrict__ bl, const float* __restrict__ br,
    unsigned short* __restrict__ OL, unsigned short* __restrict__ OR_, int K)
{
    __shared__ __align__(16) unsigned short Ah[64 * APITCH];
    __shared__ __align__(16) unsigned short Al[64 * APITCH];
    gemm_body<true>(Ah, Al, Xf, nullptr, nullptr, WThi, WTlo, bl, br, OL, OR_, K, blockIdx.x);
}

__global__ __launch_bounds__(256, 4) void k_gemm_mfma(
    const unsigned short* __restrict__ Xhi, const unsigned short* __restrict__ Xlo,
    const unsigned short* __restrict__ WThi, const unsigned short* __restrict__ WTlo,
    const float* __restrict__ bl, const float* __restrict__ br,
    unsigned short* __restrict__ OL, unsigned short* __restrict__ OR_, int K)
{
    __shared__ __align__(16) unsigned short Ah[64 * APITCH];
    __shared__ __align__(16) unsigned short Al[64 * APITCH];
    gemm_body<false>(Ah, Al, nullptr, Xhi, Xlo, WThi, WTlo, bl, br, OL, OR_, K, blockIdx.x);
}

// ---------------------------------------------------------------- edge phase
// 16-lane butterfly sum on the VALU pipe via DPP (no ds_swizzle / lgkmcnt).
__device__ __forceinline__ float red16dpp(float v) {
    v += __int_as_float(__builtin_amdgcn_update_dpp(
             0, __float_as_int(v), 0xB1, 0xF, 0xF, true));   // quad_perm [1,0,3,2]
    v += __int_as_float(__builtin_amdgcn_update_dpp(
             0, __float_as_int(v), 0x4E, 0xF, 0xF, true));   // quad_perm [2,3,0,1]
    v += __int_as_float(__builtin_amdgcn_update_dpp(
             0, __float_as_int(v), 0x141, 0xF, 0xF, true));  // row_half_mirror
    v += __int_as_float(__builtin_amdgcn_update_dpp(
             0, __float_as_int(v), 0x140, 0xF, 0xF, true));  // row_mirror
    return v;
}

// cvt 8 fp16 (uint4) -> four f32x2 (packed-f32 friendly)
__device__ __forceinline__ void cvt_h8(uint4 u, f32x2 x[4]) {
    float2 a = __half22float2(*(__half2*)&u.x);
    float2 b = __half22float2(*(__half2*)&u.y);
    float2 c = __half22float2(*(__half2*)&u.z);
    float2 d = __half22float2(*(__half2*)&u.w);
    f32x2 v0 = {a.x, a.y}; x[0] = v0;
    f32x2 v1 = {b.x, b.y}; x[1] = v1;
    f32x2 v2 = {c.x, c.y}; x[2] = v2;
    f32x2 v3 = {d.x, d.y}; x[3] = v3;
}
__device__ __forceinline__ void load_h8v(const unsigned short* base, size_t off,
                                         f32x2 x[4]) {
    uint4 u = *(const uint4*)(base + off);
    cvt_h8(u, x);
}

// att . leaky_relu(x + r) over this lane's 8 dims, packed f32x2.
__device__ __forceinline__ float dot8lk(const f32x2 x[4], const f32x2 r[4],
                                        const f32x2 a[4]) {
    f32x2 e0 = x[0] + r[0];
    f32x2 e1 = x[1] + r[1];
    f32x2 l0 = __builtin_elementwise_max(e0, NEG_SLOPE * e0);
    f32x2 l1 = __builtin_elementwise_max(e1, NEG_SLOPE * e1);
    f32x2 s0 = a[0] * l0;
    f32x2 s1 = a[1] * l1;
    f32x2 e2 = x[2] + r[2];
    f32x2 e3 = x[3] + r[3];
    f32x2 l2 = __builtin_elementwise_max(e2, NEG_SLOPE * e2);
    f32x2 l3 = __builtin_elementwise_max(e3, NEG_SLOPE * e3);
    s0 += a[2] * l2;
    s1 += a[3] * l3;
    f32x2 s = s0 + s1;
    return s.x + s.y;
}

// One wave per destination node; 4 quarters of 16 lanes each process a
// different incoming edge. 3-stage software pipeline: row-gather for block
// k+1 and col_src for block k+2 stay in flight across block k's compute
// (loop-carried deps are only acc/lsum/m). Deferred-max softmax.
__global__ __launch_bounds__(256) void k_edge(
    const unsigned short* __restrict__ xl, const unsigned short* __restrict__ xr,
    const float* __restrict__ att, const float* __restrict__ bias,
    const int* __restrict__ offsets, const int* __restrict__ col_src,
    unsigned short* __restrict__ outHi, unsigned short* __restrict__ outLo)
{
    int d = blockIdx.x * 4 + (threadIdx.x >> 6);
    if (d >= N_NODES) return;
    const int lane = threadIdx.x & 63;
    const int q = lane >> 4;
    const int t = lane & 15;
    const size_t dim0 = (size_t)t * 8;

    f32x2 rr[4], aa[4], xs[4];
    load_h8v(xr, (size_t)d * 128 + dim0, rr);
    {
        const float4 a0 = *(const float4*)(att + dim0);
        const float4 a1 = *(const float4*)(att + dim0 + 4);
        f32x2 w0 = {a0.x, a0.y}; aa[0] = w0;
        f32x2 w1 = {a0.z, a0.w}; aa[1] = w1;
        f32x2 w2 = {a1.x, a1.y}; aa[2] = w2;
        f32x2 w3 = {a1.z, a1.w}; aa[3] = w3;
    }
    load_h8v(xl, (size_t)d * 128 + dim0, xs);
    float sl = red16dpp(dot8lk(xs, rr, aa));   // identical in all 64 lanes

    // deferred-max online softmax: m is a reference >= logit-8 for all
    // accumulated terms; every quarter starts at the self-loop logit.
    float m = sl, thr = sl + 8.f;
    float lsum = (q == 0) ? 1.f : 0.f;
    f32x2 zero = {0.f, 0.f};
    f32x2 acc[4];
#pragma unroll
    for (int j = 0; j < 4; ++j) acc[j] = (q == 0) ? xs[j] : zero;

    const int ibeg = offsets[d], iend = offsets[d + 1];
    // pipeline prologue: row A in flight, src index B in flight
    int ia = ibeg + q;
    bool vA = ia < iend;
    int sA = vA ? col_src[ia] : d;
    uint4 uA = *(const uint4*)(xl + (size_t)sA * 128 + dim0);
    int ib = ia + 4;
    bool vB = ib < iend;
    int sB = vB ? col_src[ib] : d;

    for (int base = ibeg; base < iend; base += 4) {
        // issue next row-gather + next-next index before the compute
        uint4 uB = *(const uint4*)(xl + (size_t)sB * 128 + dim0);
        int ic = base + 8 + q;
        bool vC = ic < iend;
        int sC = vC ? col_src[ic] : d;

        f32x2 x[4];
        cvt_h8(uA, x);
        float logit = red16dpp(dot8lk(x, rr, aa));   // quarter-uniform
        if (__builtin_expect(logit > thr, 0)) {      // rare rescale path
            float sc = __expf(m - logit);
            lsum *= sc;
#pragma unroll
            for (int j = 0; j < 4; ++j) acc[j] = acc[j] * sc;
            m = logit; thr = logit + 8.f;
        }
        float w = vA ? __expf(logit - m) : 0.f;      // <= e^8
        lsum += w;
        f32x2 w2 = {w, w};
#pragma unroll
        for (int j = 0; j < 4; ++j) acc[j] += w2 * x[j];   // pk_fma

        uA = uB; vA = vB; sB = sC; vB = vC;          // rotate pipeline
    }

    // merge the 4 quarters (each holds partials relative to its own m)
    float M = m;
    M = fmaxf(M, __shfl_xor(M, 16));
    M = fmaxf(M, __shfl_xor(M, 32));
    float sc = __expf(m - M);
    lsum *= sc;
    f32x2 sc2 = {sc, sc};
#pragma unroll
    for (int j = 0; j < 4; ++j) acc[j] = acc[j] * sc2;
#pragma unroll
    for (int off = 16; off <= 32; off <<= 1) {
        lsum += __shfl_xor(lsum, off);
#pragma unroll
        for (int j = 0; j < 4; ++j) {
            acc[j].x += __shfl_xor(acc[j].x, off);
            acc[j].y += __shfl_xor(acc[j].y, off);
        }
    }

    if (q == 0) {
        float inv = 1.f / lsum;
        const float4 b0 = *(const float4*)(bias + dim0);
        const float4 b1 = *(const float4*)(bias + dim0 + 4);
        float bv[8] = {b0.x, b0.y, b0.z, b0.w, b1.x, b1.y, b1.z, b1.w};
        float v[8];
#pragma unroll
        for (int j = 0; j < 4; ++j) {
            v[2 * j]     = fmaxf(fmaf(acc[j].x, inv, bv[2 * j]), 0.f);
            v[2 * j + 1] = fmaxf(fmaf(acc[j].y, inv, bv[2 * j + 1]), 0.f);
        }
        union { unsigned short s[8]; uint4 u; } Hh, Ll;
#pragma unroll
        for (int i2 = 0; i2 < 8; ++i2) bsplit(v[i2], Hh.s[i2], Ll.s[i2]);
        *(uint4*)(outHi + (size_t)d * 128 + dim0) = Hh.u;
        *(uint4*)(outLo + (size_t)d * 128 + dim0) = Ll.u;
    }
}

// ---------------------------------------------------------------- pooling
__global__ __launch_bounds__(256) void k_pool(
    const unsigned short* __restrict__ hHi, const unsigned short* __restrict__ hLo,
    const int* __restrict__ batch,
    float* __restrict__ psum, float* __restrict__ pcnt)
{
    const int tid = threadIdx.x;
    const int tx = tid & 31;
    const int ty = tid >> 5;
    const int n0 = blockIdx.x * 64;
    const int d0 = tx * 4;

    float4 acc = make_float4(0.f, 0.f, 0.f, 0.f);
    int cur = -1, crun = 0;
#pragma unroll
    for (int it = 0; it < 8; ++it) {
        int n = n0 + it * 8 + ty;
        if (n < N_NODES) {
            int g = batch[n];
            if (g != cur) {
                if (cur >= 0) {
                    atomicAdd(&psum[cur * 128 + d0 + 0], acc.x);
                    atomicAdd(&psum[cur * 128 + d0 + 1], acc.y);
                    atomicAdd(&psum[cur * 128 + d0 + 2], acc.z);
                    atomicAdd(&psum[cur * 128 + d0 + 3], acc.w);
                    if (tx == 0) atomicAdd(&pcnt[cur], (float)crun);
                }
                cur = g; acc = make_float4(0.f, 0.f, 0.f, 0.f); crun = 0;
            }
            ushort4 h = *(const ushort4*)(hHi + (size_t)n * 128 + d0);
            ushort4 l = *(const ushort4*)(hLo + (size_t)n * 128 + d0);
            acc.x += bjoin(h.x, l.x);
            acc.y += bjoin(h.y, l.y);
            acc.z += bjoin(h.z, l.z);
            acc.w += bjoin(h.w, l.w);
            crun++;
        }
    }
    if (cur >= 0) {
        atomicAdd(&psum[cur * 128 + d0 + 0], acc.x);
        atomicAdd(&psum[cur * 128 + d0 + 1], acc.y);
        atomicAdd(&psum[cur * 128 + d0 + 2], acc.z);
        atomicAdd(&psum[cur * 128 + d0 + 3], acc.w);
        if (tx == 0) atomicAdd(&pcnt[cur], (float)crun);
    }
}

// ---------------------------------------------------------------- head
__global__ __launch_bounds__(256) void k_head(
    const float* __restrict__ psum, const float* __restrict__ pcnt,
    const float* __restrict__ Wlin, const float* __restrict__ blin,
    float* __restrict__ out)
{
    int g = blockIdx.x * 4 + (threadIdx.x >> 6);
    if (g >= N_GRAPH) return;
    int lane = threadIdx.x & 63;
    float c = fmaxf(pcnt[g], 1.f);
    float2 s = *(const float2*)(psum + (size_t)g * 128 + lane * 2);
    float p = (s.x * Wlin[lane * 2] + s.y * Wlin[lane * 2 + 1]) / c;
#pragma unroll
    for (int off = 32; off > 0; off >>= 1) p += __shfl_xor(p, off);
    if (lane == 0) out[g] = p + blin[0];
}

// ---------------------------------------------------------------- launch
extern "C" void kernel_launch(void* const* d_in, const int* in_sizes, int n_in,
                              void* d_out, int out_size, void* d_ws, size_t ws_size,
                              hipStream_t stream) {
    const float* x     = (const float*)d_in[0];
    const int*   ei    = (const int*)d_in[1];
    const int*   batch = (const int*)d_in[3];
    const float* Wl1 = (const float*)d_in[4],  *bl1 = (const float*)d_in[5];
    const float* Wr1 = (const float*)d_in[6],  *br1 = (const float*)d_in[7];
    const float* att1= (const float*)d_in[8],  *b1  = (const float*)d_in[9];
    const float* Wl2 = (const float*)d_in[10], *bl2 = (const float*)d_in[11];
    const float* Wr2 = (const float*)d_in[12], *br2 = (const float*)d_in[13];
    const float* att2= (const float*)d_in[14], *b2  = (const float*)d_in[15];
    const float* Wlin= (const float*)d_in[16], *blin= (const float*)d_in[17];
    float* out = (float*)d_out;

    const int* src = ei;
    const int* dst = ei + N_EDGES;

    char* p = (char*)d_ws;
    auto carve = [&](size_t bytes) {
        void* r = (void*)p;
        p += (bytes + 255) & ~(size_t)255;
        return r;
    };
    unsigned short* bufA   = (unsigned short*)carve((size_t)N_NODES * 128 * 2); // xl fp16
    unsigned short* bufB   = (unsigned short*)carve((size_t)N_NODES * 128 * 2); // xr fp16
    unsigned short* Hhi    = (unsigned short*)carve((size_t)N_NODES * 128 * 2);
    unsigned short* Hlo    = (unsigned short*)carve((size_t)N_NODES * 128 * 2);
    unsigned short* WThi   = (unsigned short*)carve(49152 * 2);
    unsigned short* WTlo   = (unsigned short*)carve(49152 * 2);
    int*            offsets= (int*)carve((size_t)(N_NODES + 1) * 4);
    int*            lrank  = (int*)carve((size_t)N_EDGES * 4);
    int*            bcnt   = (int*)carve((size_t)NBB * 4);
    int*            bbase  = (int*)carve((size_t)NBB * 4);
    int*            partials=(int*)carve(SCANA_NB * 4);
    unsigned*       ebin   = (unsigned*)carve((size_t)N_EDGES * 4);
    int*            col_src= (int*)carve((size_t)N_EDGES * 4);
    // zero region: psum | pcnt
    char* zb = (char*)carve(262144 + 2048);
    float* psum   = (float*)zb;
    float* pcnt   = (float*)(zb + 262144);
    const size_t zbytes = 262144 + 2048;

    hipMemsetAsync(zb, 0, zbytes, stream);

    // prepW + bin1 (LDS histogram, no global atomics)
    k_prep<<<NB_PW + NBLK1, 256, 0, stream>>>(
        Wl1, Wr1, Wl2, Wr2, dst, WThi, WTlo, lrank, bcnt);

    // layer-1 GEMM (K=64) straight from fp32 x
    k_gemm_f32<<<GB_GEMM, 256, 0, stream>>>(x, WThi, WTlo,
                                            bl1, br1, bufA, bufB, F_IN);

    // CSR build: scan bcnt -> scatter to bin-sorted -> per-bin offsets+fill
    k_scanA<<<SCANA_NB, 256, 0, stream>>>(bcnt, bbase, partials);
    k_scanB<<<SCANA_NB, 256, 0, stream>>>(bbase, partials);
    k_bin2 <<<(N_EDGES + 255) / 256, 256, 0, stream>>>(src, dst, lrank, bbase, ebin);
    k_bin3 <<<NBIN, 256, 0, stream>>>(ebin, bbase, offsets, col_src);

    k_edge<<<(N_NODES + 3) / 4, 256, 0, stream>>>(
        bufA, bufB, att1, b1, offsets, col_src, Hhi, Hlo);
    // layer 2 (K=128)
    k_gemm_mfma<<<GB_GEMM, 256, 0, stream>>>(Hhi, Hlo, WThi + 16384, WTlo + 16384,
                                             bl2, br2, bufA, bufB, H_DIM);
    k_edge<<<(N_NODES + 3) / 4, 256, 0, stream>>>(
        bufA, bufB, att2, b2, offsets, col_src, Hhi, Hlo);
    // pool + head
    k_pool<<<(N_NODES + 63) / 64, 256, 0, stream>>>(Hhi, Hlo, batch, psum, pcnt);
    k_head<<<(N_GRAPH + 3) / 4, 256, 0, stream>>>(psum, pcnt, Wlin, blin, out);
}